// Round 10
// baseline (165.051 us; speedup 1.0000x reference)
//
#include <hip/hip_runtime.h>
#include <hip/hip_bf16.h>
#include <math.h>

// Problem constants
#define BB 256
#define DD 512
#define LL 196
#define NN 1024
#define MM 512
#define KK 10000

// ---- output layout (float offsets) ----
#define OUT_PY 0
#define OUT_HN ((size_t)2560000)
#define OUT_CN ((size_t)2822144)
#define OUT_AL ((size_t)3084288)

// ---- workspace layout (float offsets) ----
#define OFF_PE     ((size_t)0)         // B*8*196 = 401408
#define OFF_BETA   ((size_t)401408)    // 256
#define OFF_Z      ((size_t)401664)    // B*512  = 131072
#define OFF_EMB    ((size_t)532736)    // B*512  = 131072
#define OFF_DEEP   ((size_t)663808)    // B*512  = 131072
#define OFF_EMBP   ((size_t)794880)    // 32 * B*512  = 4194304
#define OFF_GATESP ((size_t)4989184)   // 8  * B*4096 = 8388608
#define OFF_DP     ((size_t)13377792)  // 24 * B*512  = 3145728
// end 16523520 floats = 66.1 MB

typedef __attribute__((ext_vector_type(8))) short short8v;
typedef __attribute__((ext_vector_type(4))) float f32x4;

__device__ __forceinline__ unsigned short f2bf(float f) {
    unsigned int u = __builtin_bit_cast(unsigned int, f);
    u += 0x7fffu + ((u >> 16) & 1u);            // RNE
    return (unsigned short)(u >> 16);
}

// load 8 k-contiguous floats (guarded) -> bf16x8
__device__ __forceinline__ short8v stage8(const float* __restrict__ p, bool ok,
                                          int kbase, int Ktot) {
    short8v v;
    if (ok && (kbase + 7 < Ktot)) {
        const float4 x = *(const float4*)(p + kbase);
        const float4 y = *(const float4*)(p + kbase + 4);
        v[0] = (short)f2bf(x.x); v[1] = (short)f2bf(x.y);
        v[2] = (short)f2bf(x.z); v[3] = (short)f2bf(x.w);
        v[4] = (short)f2bf(y.x); v[5] = (short)f2bf(y.y);
        v[6] = (short)f2bf(y.z); v[7] = (short)f2bf(y.w);
    } else {
#pragma unroll
        for (int i = 0; i < 8; ++i) {
            const int k = kbase + i;
            v[i] = (short)f2bf((ok && k < Ktot) ? p[k] : 0.f);
        }
    }
    return v;
}

struct GSrc { const float* A; int lda; const float* B; int ldb; int ktn; int K; };

// Dual-source TN GEMM body (bf16 MFMA), 64x64 tile, BK=64, 256 threads,
// 2-deep register prefetch: ds_write of group N waits vmcnt only on N while
// group N+1's loads remain in flight -> K-step no longer pays full HBM latency.
__device__ __forceinline__ void gemm_body(
    const int bx, const int by, const int bz, const int rowBlocks,
    const GSrc s1, const GSrc s2,
    float* __restrict__ C, const int ldc, const int Ncols,
    const int ktPerSplit, const float* __restrict__ bias,
    short (*As)[64][72], short (*Bs)[64][72])
{
    const int t = threadIdx.x;
    const int row0 = bx * 64;
    const int col0 = by * 64;
    const int ktTot = s1.ktn + s2.ktn;
    const int kt0 = bz * ktPerSplit;
    const int nk = min(ktTot, kt0 + ktPerSplit) - kt0;

    const int sr = t >> 2;
    const int sk = (t & 3) << 4;
    const int bc = col0 + sr;
    const bool bok = (bc < Ncols);
    const float* aP1 = s1.A + (size_t)(row0 + sr) * s1.lda;
    const float* bP1 = s1.B + (size_t)(bok ? bc : 0) * s1.ldb;
    const float* aP2 = s2.A ? (s2.A + (size_t)(row0 + sr) * s2.lda) : aP1;
    const float* bP2 = s2.A ? (s2.B + (size_t)(bok ? bc : 0) * s2.ldb) : bP1;

    const int l = t & 63, w = t >> 6;
    const int wrow = (w >> 1) * 32, wcol = (w & 1) * 32;
    const int lr = l & 15, g = l >> 4, g8 = g * 8;

#define GLOAD(ktg, sa0_, sa1_, sb0_, sb1_)                                     \
    {                                                                          \
        const float* aR; const float* bR; int kk, Kt;                          \
        if ((ktg) < s1.ktn) { aR = aP1; bR = bP1; kk = ((ktg) << 6) + sk; Kt = s1.K; } \
        else { aR = aP2; bR = bP2; kk = (((ktg) - s1.ktn) << 6) + sk; Kt = s2.K; } \
        sa0_ = stage8(aR, true, kk, Kt);  sa1_ = stage8(aR, true, kk + 8, Kt); \
        sb0_ = stage8(bR, bok,  kk, Kt);  sb1_ = stage8(bR, bok,  kk + 8, Kt); \
    }
#define GSTORE(buf, sa0_, sa1_, sb0_, sb1_)                                    \
    {                                                                          \
        *(short8v*)&As[buf][sr][sk] = sa0_; *(short8v*)&As[buf][sr][sk + 8] = sa1_; \
        *(short8v*)&Bs[buf][sr][sk] = sb0_; *(short8v*)&Bs[buf][sr][sk + 8] = sb1_; \
    }
#define GMFMA(buf)                                                             \
    _Pragma("unroll")                                                          \
    for (int ks = 0; ks < 2; ++ks) {                                           \
        const int ko = ks * 32 + g8;                                           \
        short8v a0 = *(const short8v*)&As[buf][wrow + lr][ko];                 \
        short8v a1 = *(const short8v*)&As[buf][wrow + 16 + lr][ko];            \
        short8v b0 = *(const short8v*)&Bs[buf][wcol + lr][ko];                 \
        short8v b1 = *(const short8v*)&Bs[buf][wcol + 16 + lr][ko];            \
        acc[0][0] = __builtin_amdgcn_mfma_f32_16x16x32_bf16(a0, b0, acc[0][0], 0, 0, 0); \
        acc[0][1] = __builtin_amdgcn_mfma_f32_16x16x32_bf16(a0, b1, acc[0][1], 0, 0, 0); \
        acc[1][0] = __builtin_amdgcn_mfma_f32_16x16x32_bf16(a1, b0, acc[1][0], 0, 0, 0); \
        acc[1][1] = __builtin_amdgcn_mfma_f32_16x16x32_bf16(a1, b1, acc[1][1], 0, 0, 0); \
    }

    f32x4 acc[2][2] = {};
    short8v Aa0, Aa1, Ab0, Ab1;     // set A
    short8v Ba0, Ba1, Bb0, Bb1;     // set B

    // prologue: kt0 -> LDS[0]; kt0+1 -> set A (in flight)
    GLOAD(kt0, Aa0, Aa1, Ab0, Ab1);
    GSTORE(0, Aa0, Aa1, Ab0, Ab1);
    if (nk > 1) GLOAD(kt0 + 1, Aa0, Aa1, Ab0, Ab1);
    __syncthreads();

    int cur = 0, kt = 0;
    while (true) {
        // even step: prefetch into B, store A
        if (kt + 2 < nk) GLOAD(kt0 + kt + 2, Ba0, Ba1, Bb0, Bb1);
        GMFMA(cur);
        if (kt + 1 < nk) GSTORE(cur ^ 1, Aa0, Aa1, Ab0, Ab1);
        __syncthreads();
        cur ^= 1; if (++kt >= nk) break;
        // odd step: prefetch into A, store B
        if (kt + 2 < nk) GLOAD(kt0 + kt + 2, Aa0, Aa1, Ab0, Ab1);
        GMFMA(cur);
        if (kt + 1 < nk) GSTORE(cur ^ 1, Ba0, Ba1, Bb0, Bb1);
        __syncthreads();
        cur ^= 1; if (++kt >= nk) break;
    }

    float* Cp = C + (size_t)bz * ((size_t)rowBlocks * 64) * ldc;
#pragma unroll
    for (int m = 0; m < 2; ++m)
#pragma unroll
        for (int n = 0; n < 2; ++n)
#pragma unroll
            for (int j = 0; j < 4; ++j) {
                const int r = row0 + wrow + m * 16 + g * 4 + j;
                const int c = col0 + wcol + n * 16 + lr;
                if (c < Ncols) {
                    float v = acc[m][n][j];
                    if (bias) v += bias[c];
                    Cp[(size_t)r * ldc + c] = v;
                }
            }
#undef GLOAD
#undef GSTORE
#undef GMFMA
}

// ==== K1: att_e (2048) || emb GEMM (1024) || gates_h GEMM (1024) ====
// att_e: block (b, ch): stage 64-row slab (50 KB) of a_i[b] into LDS with
// dense all-lane float4 loads (12-13/thread in flight), then thread t<196
// accumulates its column over 64 d (conflict-free stride-196 LDS reads).
__global__ __launch_bounds__(256) void k1_atte_emb_gatesh(
    const float* __restrict__ a_i, const float* __restrict__ f_att_w,
    float* __restrict__ pe,
    const float* __restrict__ inp, const float* __restrict__ E_w,
    float* __restrict__ embp,
    const float* __restrict__ h, const float* __restrict__ W_ih,
    const float* __restrict__ W_hh, float* __restrict__ gatesp)
{
    __shared__ __align__(16) unsigned char smem[52224];
    const int bid = blockIdx.x;
    const int t = threadIdx.x;

    if (bid < 2048) {
        float* lds = (float*)smem;                    // [64*196]
        const int b = bid >> 3, ch = bid & 7;
        const float4* g4 = (const float4*)(a_i + ((size_t)b * DD + ch * 64) * LL);
        float4* l4 = (float4*)lds;
#pragma unroll
        for (int i = 0; i < 12; ++i) l4[t + i * 256] = g4[t + i * 256];
        if (t < 64) l4[t + 3072] = g4[t + 3072];
        __syncthreads();
        if (t < LL) {
            const float* wp = f_att_w + ch * 64;
            float e = 0.f;
#pragma unroll 16
            for (int d = 0; d < 64; ++d) e += lds[d * LL + t] * wp[d];
            pe[((size_t)b * 8 + ch) * LL + t] = e;
        }
    } else if (bid < 3072) {
        short (*As)[64][72] = (short (*)[64][72])smem;
        short (*Bs)[64][72] = (short (*)[64][72])(smem + 18432);
        const int i = bid - 2048;                     // 1024 = 4*8*32
        GSrc s1 = {inp, KK, E_w, KK, 157, KK};
        GSrc s2 = {nullptr, 0, nullptr, 0, 0, 0};
        gemm_body(i & 3, (i >> 2) & 7, i >> 5, 4, s1, s2,
                  embp, MM, MM, 5, nullptr, As, Bs);
    } else {
        short (*As)[64][72] = (short (*)[64][72])smem;
        short (*Bs)[64][72] = (short (*)[64][72])(smem + 18432);
        const int i = bid - 3072;                     // 1024 = 4*64*4
        GSrc s1 = {h, NN, W_ih + 512, 2048, 16, NN};
        GSrc s2 = {h, NN, W_hh, NN, 16, NN};
        gemm_body(i & 3, (i >> 2) & 63, i >> 8, 4, s1, s2,
                  gatesp, 4096, 4096, 8, nullptr, As, Bs);
    }
}

// ==== K2: softmax+beta (256) || emb partial reduce (512) ====
__global__ __launch_bounds__(256) void k2_softmax_embred(
    const float* __restrict__ pe, const float* __restrict__ h,
    const float* __restrict__ f_att_w, const float* __restrict__ f_att_b,
    const float* __restrict__ gate_w, const float* __restrict__ gate_b,
    float* __restrict__ alpha_out, float* __restrict__ beta,
    const float* __restrict__ embp, const float* __restrict__ E_b,
    float* __restrict__ emb)
{
    const int bid = blockIdx.x;
    const int t = threadIdx.x;
    if (bid < 256) {
        const int b = bid;
        __shared__ float red[256];
        __shared__ float red2[256];
        const float4 h4 = *(const float4*)(h + (size_t)b * NN + t * 4);
        const float4 w4 = *(const float4*)(f_att_w + DD + t * 4);
        const float4 g4 = *(const float4*)(gate_w + t * 4);
        float hd = h4.x * w4.x + h4.y * w4.y + h4.z * w4.z + h4.w * w4.w;
        float gd = h4.x * g4.x + h4.y * g4.y + h4.z * g4.z + h4.w * g4.w;
        red[t] = hd; red2[t] = gd;
        __syncthreads();
        for (int s = 128; s > 0; s >>= 1) {
            if (t < s) { red[t] += red[t + s]; red2[t] += red2[t + s]; }
            __syncthreads();
        }
        const float hdot = red[0];
        const float gdot = red2[0];
        __syncthreads();
        float e = -3.4e38f;
        if (t < LL) {
            const float* p = pe + (size_t)b * 8 * LL + t;
            e = hdot + f_att_b[0];
#pragma unroll
            for (int ch = 0; ch < 8; ++ch) e += p[ch * LL];
        }
        red[t] = e;
        __syncthreads();
        for (int s = 128; s > 0; s >>= 1) {
            if (t < s) red[t] = fmaxf(red[t], red[t + s]);
            __syncthreads();
        }
        const float mx = red[0];
        __syncthreads();
        const float ex = (t < LL) ? expf(e - mx) : 0.f;
        red[t] = ex;
        __syncthreads();
        for (int s = 128; s > 0; s >>= 1) {
            if (t < s) red[t] += red[t + s];
            __syncthreads();
        }
        const float inv = 1.f / red[0];
        if (t < LL) alpha_out[(size_t)b * LL + t] = ex * inv;
        if (t == 0) beta[b] = 1.f / (1.f + expf(-(gdot + gate_b[0])));
    } else {
        const int idx = (bid - 256) * 256 + t;        // < B*512
        const int j = idx & 511;
        float v = E_b[j];
#pragma unroll
        for (int s = 0; s < 32; ++s) v += embp[(size_t)s * (BB * 512) + idx];
        emb[idx] = v;
    }
}

// ==== K3: att_z (2048, LDS-staged slab, L3-hot) || gates_e GEMM (512) ====
__global__ __launch_bounds__(256) void k3_attz_gatese(
    const float* __restrict__ a_i, const float* __restrict__ alpha,
    const float* __restrict__ beta, float* __restrict__ z,
    const float* __restrict__ emb, const float* __restrict__ W_ih,
    float* __restrict__ gatesp_e)
{
    __shared__ __align__(16) unsigned char smem[52224];
    const int bid = blockIdx.x;
    const int t = threadIdx.x;

    if (bid < 2048) {
        float* lds = (float*)smem;                    // [64*196]
        float* al  = lds + 64 * LL;                   // [196]
        const int b = bid >> 3, ch = bid & 7;
        const float4* g4 = (const float4*)(a_i + ((size_t)b * DD + ch * 64) * LL);
        float4* l4 = (float4*)lds;
#pragma unroll
        for (int i = 0; i < 12; ++i) l4[t + i * 256] = g4[t + i * 256];
        if (t < 64) l4[t + 3072] = g4[t + 3072];
        if (t < LL) al[t] = alpha[(size_t)b * LL + t];
        __syncthreads();
        // thread t: row r=t>>2 (slab row), quarter q=t&3 covers l=q*49..q*49+48
        const int r = t >> 2, q = t & 3;
        const float* rowp = lds + r * LL + q * 49;
        const float* alq  = al + q * 49;
        float s = 0.f;
#pragma unroll 7
        for (int j = 0; j < 49; ++j) s += rowp[j] * alq[j];
        s += __shfl_xor(s, 1, 64);
        s += __shfl_xor(s, 2, 64);
        if (q == 0) z[(size_t)b * DD + ch * 64 + r] = beta[b] * s;
    } else {
        short (*As)[64][72] = (short (*)[64][72])smem;
        short (*Bs)[64][72] = (short (*)[64][72])(smem + 18432);
        const int i = bid - 2048;                     // 512 = 4*64*2
        GSrc s1 = {emb, MM, W_ih, 2048, 8, MM};
        GSrc s2 = {nullptr, 0, nullptr, 0, 0, 0};
        gemm_body(i & 3, (i >> 2) & 63, i >> 8, 4, s1, s2,
                  gatesp_e, 4096, 4096, 4, nullptr, As, Bs);
    }
}

// ==== K4: gates_z GEMM (512) || lz GEMM (256) ====
__global__ __launch_bounds__(256) void k4_gatesz_lz(
    const float* __restrict__ z, const float* __restrict__ W_ih,
    float* __restrict__ gatesp_z,
    const float* __restrict__ Lz_w, float* __restrict__ dp)
{
    __shared__ __align__(16) unsigned char smem[36864];
    short (*As)[64][72] = (short (*)[64][72])smem;
    short (*Bs)[64][72] = (short (*)[64][72])(smem + 18432);
    const int bid = blockIdx.x;
    if (bid < 512) {                                  // 4*64*2
        GSrc s1 = {z, DD, W_ih + 1536, 2048, 8, DD};
        GSrc s2 = {nullptr, 0, nullptr, 0, 0, 0};
        gemm_body(bid & 3, (bid >> 2) & 63, bid >> 8, 4, s1, s2,
                  gatesp_z, 4096, 4096, 4, nullptr, As, Bs);
    } else {
        const int i = bid - 512;                      // 256 = 4*8*8
        GSrc s1 = {z, DD, Lz_w, DD, 8, DD};
        GSrc s2 = {nullptr, 0, nullptr, 0, 0, 0};
        gemm_body(i & 3, (i >> 2) & 7, i >> 5, 4, s1, s2,
                  dp, MM, MM, 1, nullptr, As, Bs);
    }
}

// ==== K5: LSTM cell (sums 8 gate slices) ====
__global__ __launch_bounds__(256) void k5_lstm(
    const float* __restrict__ gatesp,
    const float* __restrict__ b_ih, const float* __restrict__ b_hh,
    const float* __restrict__ c_prev, float* __restrict__ hn, float* __restrict__ cn)
{
    const int idx = blockIdx.x * 256 + threadIdx.x;   // < B*1024
    const int b = idx >> 10, n = idx & 1023;
    float g[4];
#pragma unroll
    for (int gi = 0; gi < 4; ++gi) {
        const int col = gi * 1024 + n;
        const size_t o = (size_t)b * 4096 + col;
        float v = b_ih[col] + b_hh[col];
#pragma unroll
        for (int s = 0; s < 8; ++s) v += gatesp[(size_t)s * (BB * 4096) + o];
        g[gi] = v;
    }
    const float si = 1.f / (1.f + expf(-g[0]));
    const float sf = 1.f / (1.f + expf(-g[1]));
    const float so = 1.f / (1.f + expf(-g[3]));
    const float tg = tanhf(g[2]);
    const float c = c_prev[idx];
    const float cnv = sf * c + si * tg;
    const float hnv = so * tanhf(cnv);
    cn[idx] = cnv;
    hn[idx] = hnv;
}

// ==== K6: lh GEMM (512 blocks) ====
__global__ __launch_bounds__(256) void k6_lh(
    const float* __restrict__ hn, const float* __restrict__ Lh_w,
    float* __restrict__ dp_hi)
{
    __shared__ __align__(16) unsigned char smem[36864];
    short (*As)[64][72] = (short (*)[64][72])smem;
    short (*Bs)[64][72] = (short (*)[64][72])(smem + 18432);
    const int bid = blockIdx.x;                       // 512 = 4*8*16
    GSrc s1 = {hn, NN, Lh_w, NN, 16, NN};
    GSrc s2 = {nullptr, 0, nullptr, 0, 0, 0};
    gemm_body(bid & 3, (bid >> 2) & 7, bid >> 5, 4, s1, s2,
              dp_hi, MM, MM, 1, nullptr, As, Bs);
}

// ==== K7: build deep ====
__global__ __launch_bounds__(256) void k7_deep(
    const float* __restrict__ emb, const float* __restrict__ dp,
    const float* __restrict__ Lh_b, const float* __restrict__ Lz_b,
    float* __restrict__ deep)
{
    const int idx = blockIdx.x * 256 + threadIdx.x;   // < B*512
    const int j = idx & 511;
    float v = emb[idx] + Lh_b[j] + Lz_b[j];
#pragma unroll
    for (int s = 0; s < 24; ++s) v += dp[(size_t)s * (BB * 512) + idx];
    deep[idx] = v;
}

// ==== K8: p_yt GEMM (628 blocks) ====
__global__ __launch_bounds__(256) void k8_pyt(
    const float* __restrict__ deep, const float* __restrict__ Lo_w,
    const float* __restrict__ Lo_b, float* __restrict__ out)
{
    __shared__ __align__(16) unsigned char smem[36864];
    short (*As)[64][72] = (short (*)[64][72])smem;
    short (*Bs)[64][72] = (short (*)[64][72])(smem + 18432);
    const int bid = blockIdx.x;                       // 628 = 4*157
    GSrc s1 = {deep, MM, Lo_w, MM, 8, MM};
    GSrc s2 = {nullptr, 0, nullptr, 0, 0, 0};
    gemm_body(bid & 3, bid >> 2, 0, 4, s1, s2,
              out, KK, KK, 8, Lo_b, As, Bs);
}

extern "C" void kernel_launch(void* const* d_in, const int* in_sizes, int n_in,
                              void* d_out, int out_size, void* d_ws, size_t ws_size,
                              hipStream_t stream)
{
    const float* a_i     = (const float*)d_in[0];
    const float* inp     = (const float*)d_in[1];
    const float* hn_prev = (const float*)d_in[2];
    const float* cn_prev = (const float*)d_in[3];
    const float* f_att_w = (const float*)d_in[4];
    const float* f_att_b = (const float*)d_in[5];
    const float* gate_w  = (const float*)d_in[6];
    const float* gate_b  = (const float*)d_in[7];
    const float* E_w     = (const float*)d_in[8];
    const float* E_b     = (const float*)d_in[9];
    const float* W_ih    = (const float*)d_in[10];
    const float* W_hh    = (const float*)d_in[11];
    const float* b_ih    = (const float*)d_in[12];
    const float* b_hh    = (const float*)d_in[13];
    const float* Lh_w    = (const float*)d_in[14];
    const float* Lh_b    = (const float*)d_in[15];
    const float* Lz_w    = (const float*)d_in[16];
    const float* Lz_b    = (const float*)d_in[17];
    const float* Lo_w    = (const float*)d_in[18];
    const float* Lo_b    = (const float*)d_in[19];

    float* out = (float*)d_out;
    float* ws  = (float*)d_ws;

    float* PE     = ws + OFF_PE;
    float* BETA   = ws + OFF_BETA;
    float* Z      = ws + OFF_Z;
    float* EMB    = ws + OFF_EMB;
    float* DEEP   = ws + OFF_DEEP;
    float* EMBP   = ws + OFF_EMBP;
    float* GATESP = ws + OFF_GATESP;
    float* DP     = ws + OFF_DP;

    // K1: att_e (LDS-staged) || emb GEMM (32 splits) || gates_h GEMM
    k1_atte_emb_gatesh<<<4096, 256, 0, stream>>>(
        a_i, f_att_w, PE, inp, E_w, EMBP, hn_prev, W_ih, W_hh, GATESP);

    // K2: softmax+beta || emb reduce (32 slices)
    k2_softmax_embred<<<768, 256, 0, stream>>>(PE, hn_prev, f_att_w, f_att_b,
                                               gate_w, gate_b, out + OUT_AL, BETA,
                                               EMBP, E_b, EMB);

    // K3: att_z (LDS-staged, L3-hot) || gates_e GEMM (slices 4..5)
    k3_attz_gatese<<<2560, 256, 0, stream>>>(a_i, out + OUT_AL, BETA, Z,
                                             EMB, W_ih,
                                             GATESP + (size_t)4 * BB * 4096);

    // K4: gates_z GEMM (slices 6..7) || lz GEMM (dp slices 0..7)
    k4_gatesz_lz<<<768, 256, 0, stream>>>(Z, W_ih,
                                          GATESP + (size_t)6 * BB * 4096,
                                          Lz_w, DP);

    // K5: LSTM cell
    k5_lstm<<<1024, 256, 0, stream>>>(GATESP, b_ih, b_hh, cn_prev,
                                      out + OUT_HN, out + OUT_CN);

    // K6: hn@Lh_w^T (dp slices 8..23)
    k6_lh<<<512, 256, 0, stream>>>(out + OUT_HN, Lh_w,
                                   DP + (size_t)8 * BB * 512);

    // K7: deep = emb + sum(dp) + biases
    k7_deep<<<512, 256, 0, stream>>>(EMB, DP, Lh_b, Lz_b, DEEP);

    // K8: p_yt = deep @ Lo_w^T + Lo_b
    k8_pyt<<<628, 256, 0, stream>>>(DEEP, Lo_w, Lo_b, out + OUT_PY);
}

// Round 11
// 156.709 us; speedup vs baseline: 1.0532x; 1.0532x over previous
//
#include <hip/hip_runtime.h>
#include <hip/hip_bf16.h>
#include <math.h>

// Problem constants
#define BB 256
#define DD 512
#define LL 196
#define NN 1024
#define MM 512
#define KK 10000

// ---- output layout (float offsets) ----
#define OUT_PY 0
#define OUT_HN ((size_t)2560000)
#define OUT_CN ((size_t)2822144)
#define OUT_AL ((size_t)3084288)

// ---- workspace layout (float offsets) ----
#define OFF_PE     ((size_t)0)         // B*16*196 = 802816
#define OFF_BETA   ((size_t)802816)    // 256
#define OFF_Z      ((size_t)803072)    // B*512  = 131072
#define OFF_EMB    ((size_t)934144)    // B*512  = 131072
#define OFF_DEEP   ((size_t)1065216)   // B*512  = 131072
#define OFF_EMBP   ((size_t)1196288)   // 32 * B*512  = 4194304
#define OFF_GATESP ((size_t)5390592)   // 8  * B*4096 = 8388608
#define OFF_DP     ((size_t)13779200)  // 24 * B*512  = 3145728
// end 16924928 floats = 67.7 MB

typedef __attribute__((ext_vector_type(8))) short short8v;
typedef __attribute__((ext_vector_type(4))) float f32x4;

__device__ __forceinline__ unsigned short f2bf(float f) {
    unsigned int u = __builtin_bit_cast(unsigned int, f);
    u += 0x7fffu + ((u >> 16) & 1u);            // RNE
    return (unsigned short)(u >> 16);
}

// fire-and-forget 16B global->LDS copy (no VGPR round-trip)
__device__ __forceinline__ void gl_lds16(const float* g, float* l) {
    __builtin_amdgcn_global_load_lds(
        (const __attribute__((address_space(1))) void*)g,
        (__attribute__((address_space(3))) void*)l, 16, 0, 0);
}

// load 8 k-contiguous floats (guarded) -> bf16x8
__device__ __forceinline__ short8v stage8(const float* __restrict__ p, bool ok,
                                          int kbase, int Ktot) {
    short8v v;
    if (ok && (kbase + 7 < Ktot)) {
        const float4 x = *(const float4*)(p + kbase);
        const float4 y = *(const float4*)(p + kbase + 4);
        v[0] = (short)f2bf(x.x); v[1] = (short)f2bf(x.y);
        v[2] = (short)f2bf(x.z); v[3] = (short)f2bf(x.w);
        v[4] = (short)f2bf(y.x); v[5] = (short)f2bf(y.y);
        v[6] = (short)f2bf(y.z); v[7] = (short)f2bf(y.w);
    } else {
#pragma unroll
        for (int i = 0; i < 8; ++i) {
            const int k = kbase + i;
            v[i] = (short)f2bf((ok && k < Ktot) ? p[k] : 0.f);
        }
    }
    return v;
}

struct GSrc { const float* A; int lda; const float* B; int ldb; int ktn; int K; };

// Dual-source TN GEMM body (bf16 MFMA), 64x64 tile, BK=64, 256 threads,
// 1-deep register prefetch (round-9 proven).
__device__ __forceinline__ void gemm_body(
    const int bx, const int by, const int bz, const int rowBlocks,
    const GSrc s1, const GSrc s2,
    float* __restrict__ C, const int ldc, const int Ncols,
    const int ktPerSplit, const float* __restrict__ bias,
    short (*As)[64][72], short (*Bs)[64][72])
{
    const int t = threadIdx.x;
    const int row0 = bx * 64;
    const int col0 = by * 64;
    const int ktTot = s1.ktn + s2.ktn;
    const int kt0 = bz * ktPerSplit;
    const int nk = min(ktTot, kt0 + ktPerSplit) - kt0;

    const int sr = t >> 2;
    const int sk = (t & 3) << 4;
    const int bc = col0 + sr;
    const bool bok = (bc < Ncols);
    const float* aP1 = s1.A + (size_t)(row0 + sr) * s1.lda;
    const float* bP1 = s1.B + (size_t)(bok ? bc : 0) * s1.ldb;
    const float* aP2 = s2.A ? (s2.A + (size_t)(row0 + sr) * s2.lda) : aP1;
    const float* bP2 = s2.A ? (s2.B + (size_t)(bok ? bc : 0) * s2.ldb) : bP1;

    const int l = t & 63, w = t >> 6;
    const int wrow = (w >> 1) * 32, wcol = (w & 1) * 32;
    const int lr = l & 15, g = l >> 4, g8 = g * 8;

    f32x4 acc[2][2] = {};

    short8v sa0, sa1, sb0, sb1;
    {
        const int ktg = kt0;
        const float* aR; const float* bR; int kk, Kt;
        if (ktg < s1.ktn) { aR = aP1; bR = bP1; kk = (ktg << 6) + sk; Kt = s1.K; }
        else              { aR = aP2; bR = bP2; kk = ((ktg - s1.ktn) << 6) + sk; Kt = s2.K; }
        sa0 = stage8(aR, true, kk, Kt);  sa1 = stage8(aR, true, kk + 8, Kt);
        sb0 = stage8(bR, bok,  kk, Kt);  sb1 = stage8(bR, bok,  kk + 8, Kt);
    }
    *(short8v*)&As[0][sr][sk] = sa0; *(short8v*)&As[0][sr][sk + 8] = sa1;
    *(short8v*)&Bs[0][sr][sk] = sb0; *(short8v*)&Bs[0][sr][sk + 8] = sb1;
    __syncthreads();

    int cur = 0;
    for (int kt = 0; kt < nk; ++kt) {
        const bool more = (kt + 1 < nk);
        if (more) {
            const int ktg = kt0 + kt + 1;
            const float* aR; const float* bR; int kk, Kt;
            if (ktg < s1.ktn) { aR = aP1; bR = bP1; kk = (ktg << 6) + sk; Kt = s1.K; }
            else              { aR = aP2; bR = bP2; kk = ((ktg - s1.ktn) << 6) + sk; Kt = s2.K; }
            sa0 = stage8(aR, true, kk, Kt);  sa1 = stage8(aR, true, kk + 8, Kt);
            sb0 = stage8(bR, bok,  kk, Kt);  sb1 = stage8(bR, bok,  kk + 8, Kt);
        }
#pragma unroll
        for (int ks = 0; ks < 2; ++ks) {
            const int ko = ks * 32 + g8;
            short8v a0 = *(const short8v*)&As[cur][wrow + lr][ko];
            short8v a1 = *(const short8v*)&As[cur][wrow + 16 + lr][ko];
            short8v b0 = *(const short8v*)&Bs[cur][wcol + lr][ko];
            short8v b1 = *(const short8v*)&Bs[cur][wcol + 16 + lr][ko];
            acc[0][0] = __builtin_amdgcn_mfma_f32_16x16x32_bf16(a0, b0, acc[0][0], 0, 0, 0);
            acc[0][1] = __builtin_amdgcn_mfma_f32_16x16x32_bf16(a0, b1, acc[0][1], 0, 0, 0);
            acc[1][0] = __builtin_amdgcn_mfma_f32_16x16x32_bf16(a1, b0, acc[1][0], 0, 0, 0);
            acc[1][1] = __builtin_amdgcn_mfma_f32_16x16x32_bf16(a1, b1, acc[1][1], 0, 0, 0);
        }
        if (more) {
            *(short8v*)&As[cur ^ 1][sr][sk] = sa0;
            *(short8v*)&As[cur ^ 1][sr][sk + 8] = sa1;
            *(short8v*)&Bs[cur ^ 1][sr][sk] = sb0;
            *(short8v*)&Bs[cur ^ 1][sr][sk + 8] = sb1;
        }
        __syncthreads();
        cur ^= 1;
    }

    float* Cp = C + (size_t)bz * ((size_t)rowBlocks * 64) * ldc;
#pragma unroll
    for (int m = 0; m < 2; ++m)
#pragma unroll
        for (int n = 0; n < 2; ++n)
#pragma unroll
            for (int j = 0; j < 4; ++j) {
                const int r = row0 + wrow + m * 16 + g * 4 + j;
                const int c = col0 + wcol + n * 16 + lr;
                if (c < Ncols) {
                    float v = acc[m][n][j];
                    if (bias) v += bias[c];
                    Cp[(size_t)r * ldc + c] = v;
                }
            }
}

// ==== L1: att_e slab kernel (4096 blocks, 6 blocks/CU) ====
// block (b,ch): stage 32-row slab (25088 B contiguous) of a_i via
// global_load_lds (7 issues/thread, zero VGPR), then thread t<196 reduces
// its column over 32 d (conflict-free stride-196 LDS reads).
__global__ __launch_bounds__(256) void att_e_slab(
    const float* __restrict__ a_i, const float* __restrict__ f_att_w,
    float* __restrict__ pe)
{
    __shared__ __align__(16) float slab[6280];
    const int t = threadIdx.x;
    const int b = blockIdx.x >> 4, ch = blockIdx.x & 15;
    const int w = t >> 6, lane = t & 63;
    const float* gbase = a_i + ((size_t)b * DD + ch * 32) * LL;
#pragma unroll
    for (int k = 0; k < 7; ++k) {
        const int cw = k * 256 + w * 64;          // wave-uniform chunk base
        if (cw + lane < 1568)
            gl_lds16(gbase + (size_t)(cw + lane) * 4, slab + (size_t)cw * 4);
    }
    if (t < 8) slab[6272 + t] = 0.f;
    asm volatile("s_waitcnt vmcnt(0)" ::: "memory");
    __syncthreads();
    if (t < LL) {
        const float* wp = f_att_w + ch * 32;
        float e = 0.f;
#pragma unroll
        for (int d = 0; d < 32; ++d) e += slab[d * LL + t] * wp[d];
        pe[((size_t)b * 16 + ch) * LL + t] = e;
    }
}

// ==== L4: att_z slab kernel (4096 blocks) — a_i now L3-resident ====
__global__ __launch_bounds__(256) void att_z_slab(
    const float* __restrict__ a_i, const float* __restrict__ alpha,
    const float* __restrict__ beta, float* __restrict__ z)
{
    __shared__ __align__(16) float slab[6280];
    __shared__ float al[200];
    const int t = threadIdx.x;
    const int b = blockIdx.x >> 4, ch = blockIdx.x & 15;
    const int w = t >> 6, lane = t & 63;
    const float* gbase = a_i + ((size_t)b * DD + ch * 32) * LL;
#pragma unroll
    for (int k = 0; k < 7; ++k) {
        const int cw = k * 256 + w * 64;
        if (cw + lane < 1568)
            gl_lds16(gbase + (size_t)(cw + lane) * 4, slab + (size_t)cw * 4);
    }
    if (t < 200) al[t] = (t < LL) ? alpha[(size_t)b * LL + t] : 0.f;
    if (t < 8) slab[6272 + t] = 0.f;
    asm volatile("s_waitcnt vmcnt(0)" ::: "memory");
    __syncthreads();
    // 8 threads per slab row; quarter q covers l = q*25 .. q*25+24 (al pad 0)
    const int r = t >> 3, q = t & 7;
    const float* rowp = slab + r * LL + q * 25;
    const float* alq  = al + q * 25;
    float s = 0.f;
#pragma unroll
    for (int j = 0; j < 25; ++j) s += rowp[j] * alq[j];
    s += __shfl_xor(s, 1, 64);
    s += __shfl_xor(s, 2, 64);
    s += __shfl_xor(s, 4, 64);
    if (q == 0) z[(size_t)b * DD + ch * 32 + r] = beta[b] * s;
}

// ==== L2: emb GEMM (1024) || gates_h GEMM (1024) ====
__global__ __launch_bounds__(256) void l2_emb_gatesh(
    const float* __restrict__ inp, const float* __restrict__ E_w,
    float* __restrict__ embp,
    const float* __restrict__ h, const float* __restrict__ W_ih,
    const float* __restrict__ W_hh, float* __restrict__ gatesp)
{
    __shared__ __align__(16) short As[2][64][72];
    __shared__ __align__(16) short Bs[2][64][72];
    const int bid = blockIdx.x;
    if (bid < 1024) {                                 // 4*8*32
        GSrc s1 = {inp, KK, E_w, KK, 157, KK};
        GSrc s2 = {nullptr, 0, nullptr, 0, 0, 0};
        gemm_body(bid & 3, (bid >> 2) & 7, bid >> 5, 4, s1, s2,
                  embp, MM, MM, 5, nullptr, As, Bs);
    } else {
        const int i = bid - 1024;                     // 1024 = 4*64*4
        GSrc s1 = {h, NN, W_ih + 512, 2048, 16, NN};
        GSrc s2 = {h, NN, W_hh, NN, 16, NN};
        gemm_body(i & 3, (i >> 2) & 63, i >> 8, 4, s1, s2,
                  gatesp, 4096, 4096, 8, nullptr, As, Bs);
    }
}

// ==== L3: softmax+beta (256) || emb partial reduce (512) ====
__global__ __launch_bounds__(256) void l3_softmax_embred(
    const float* __restrict__ pe, const float* __restrict__ h,
    const float* __restrict__ f_att_w, const float* __restrict__ f_att_b,
    const float* __restrict__ gate_w, const float* __restrict__ gate_b,
    float* __restrict__ alpha_out, float* __restrict__ beta,
    const float* __restrict__ embp, const float* __restrict__ E_b,
    float* __restrict__ emb)
{
    const int bid = blockIdx.x;
    const int t = threadIdx.x;
    if (bid < 256) {
        const int b = bid;
        __shared__ float red[256];
        __shared__ float red2[256];
        const float4 h4 = *(const float4*)(h + (size_t)b * NN + t * 4);
        const float4 w4 = *(const float4*)(f_att_w + DD + t * 4);
        const float4 g4 = *(const float4*)(gate_w + t * 4);
        float hd = h4.x * w4.x + h4.y * w4.y + h4.z * w4.z + h4.w * w4.w;
        float gd = h4.x * g4.x + h4.y * g4.y + h4.z * g4.z + h4.w * g4.w;
        red[t] = hd; red2[t] = gd;
        __syncthreads();
        for (int s = 128; s > 0; s >>= 1) {
            if (t < s) { red[t] += red[t + s]; red2[t] += red2[t + s]; }
            __syncthreads();
        }
        const float hdot = red[0];
        const float gdot = red2[0];
        __syncthreads();
        float e = -3.4e38f;
        if (t < LL) {
            const float* p = pe + (size_t)b * 16 * LL + t;
            e = hdot + f_att_b[0];
#pragma unroll
            for (int ch = 0; ch < 16; ++ch) e += p[ch * LL];
        }
        red[t] = e;
        __syncthreads();
        for (int s = 128; s > 0; s >>= 1) {
            if (t < s) red[t] = fmaxf(red[t], red[t + s]);
            __syncthreads();
        }
        const float mx = red[0];
        __syncthreads();
        const float ex = (t < LL) ? expf(e - mx) : 0.f;
        red[t] = ex;
        __syncthreads();
        for (int s = 128; s > 0; s >>= 1) {
            if (t < s) red[t] += red[t + s];
            __syncthreads();
        }
        const float inv = 1.f / red[0];
        if (t < LL) alpha_out[(size_t)b * LL + t] = ex * inv;
        if (t == 0) beta[b] = 1.f / (1.f + expf(-(gdot + gate_b[0])));
    } else {
        const int idx = (bid - 256) * 256 + t;        // < B*512
        const int j = idx & 511;
        float v = E_b[j];
#pragma unroll
        for (int s = 0; s < 32; ++s) v += embp[(size_t)s * (BB * 512) + idx];
        emb[idx] = v;
    }
}

// ==== L5: gates_e (512) || gates_z (512) || lz (256) ====
__global__ __launch_bounds__(256) void l5_gatesez_lz(
    const float* __restrict__ emb, const float* __restrict__ z,
    const float* __restrict__ W_ih, float* __restrict__ gatesp,
    const float* __restrict__ Lz_w, float* __restrict__ dp)
{
    __shared__ __align__(16) short As[2][64][72];
    __shared__ __align__(16) short Bs[2][64][72];
    const int bid = blockIdx.x;
    if (bid < 512) {                                  // 4*64*2 -> slices 4..5
        GSrc s1 = {emb, MM, W_ih, 2048, 8, MM};
        GSrc s2 = {nullptr, 0, nullptr, 0, 0, 0};
        gemm_body(bid & 3, (bid >> 2) & 63, bid >> 8, 4, s1, s2,
                  gatesp + (size_t)4 * BB * 4096, 4096, 4096, 4, nullptr, As, Bs);
    } else if (bid < 1024) {                          // slices 6..7
        const int i = bid - 512;
        GSrc s1 = {z, DD, W_ih + 1536, 2048, 8, DD};
        GSrc s2 = {nullptr, 0, nullptr, 0, 0, 0};
        gemm_body(i & 3, (i >> 2) & 63, i >> 8, 4, s1, s2,
                  gatesp + (size_t)6 * BB * 4096, 4096, 4096, 4, nullptr, As, Bs);
    } else {
        const int i = bid - 1024;                     // 256 = 4*8*8 -> dp 0..7
        GSrc s1 = {z, DD, Lz_w, DD, 8, DD};
        GSrc s2 = {nullptr, 0, nullptr, 0, 0, 0};
        gemm_body(i & 3, (i >> 2) & 7, i >> 5, 4, s1, s2,
                  dp, MM, MM, 1, nullptr, As, Bs);
    }
}

// ==== L6: LSTM cell (sums 8 gate slices) ====
__global__ __launch_bounds__(256) void l6_lstm(
    const float* __restrict__ gatesp,
    const float* __restrict__ b_ih, const float* __restrict__ b_hh,
    const float* __restrict__ c_prev, float* __restrict__ hn, float* __restrict__ cn)
{
    const int idx = blockIdx.x * 256 + threadIdx.x;   // < B*1024
    const int b = idx >> 10, n = idx & 1023;
    float g[4];
#pragma unroll
    for (int gi = 0; gi < 4; ++gi) {
        const int col = gi * 1024 + n;
        const size_t o = (size_t)b * 4096 + col;
        float v = b_ih[col] + b_hh[col];
#pragma unroll
        for (int s = 0; s < 8; ++s) v += gatesp[(size_t)s * (BB * 4096) + o];
        g[gi] = v;
    }
    const float si = 1.f / (1.f + expf(-g[0]));
    const float sf = 1.f / (1.f + expf(-g[1]));
    const float so = 1.f / (1.f + expf(-g[3]));
    const float tg = tanhf(g[2]);
    const float c = c_prev[idx];
    const float cnv = sf * c + si * tg;
    const float hnv = so * tanhf(cnv);
    cn[idx] = cnv;
    hn[idx] = hnv;
}

// ==== L7: lh GEMM (512 blocks, dp slices 8..23) ====
__global__ __launch_bounds__(256) void l7_lh(
    const float* __restrict__ hn, const float* __restrict__ Lh_w,
    float* __restrict__ dp_hi)
{
    __shared__ __align__(16) short As[2][64][72];
    __shared__ __align__(16) short Bs[2][64][72];
    const int bid = blockIdx.x;                       // 512 = 4*8*16
    GSrc s1 = {hn, NN, Lh_w, NN, 16, NN};
    GSrc s2 = {nullptr, 0, nullptr, 0, 0, 0};
    gemm_body(bid & 3, (bid >> 2) & 7, bid >> 5, 4, s1, s2,
              dp_hi, MM, MM, 1, nullptr, As, Bs);
}

// ==== L8: build deep ====
__global__ __launch_bounds__(256) void l8_deep(
    const float* __restrict__ emb, const float* __restrict__ dp,
    const float* __restrict__ Lh_b, const float* __restrict__ Lz_b,
    float* __restrict__ deep)
{
    const int idx = blockIdx.x * 256 + threadIdx.x;   // < B*512
    const int j = idx & 511;
    float v = emb[idx] + Lh_b[j] + Lz_b[j];
#pragma unroll
    for (int s = 0; s < 24; ++s) v += dp[(size_t)s * (BB * 512) + idx];
    deep[idx] = v;
}

// ==== L9: p_yt GEMM (628 blocks) ====
__global__ __launch_bounds__(256) void l9_pyt(
    const float* __restrict__ deep, const float* __restrict__ Lo_w,
    const float* __restrict__ Lo_b, float* __restrict__ out)
{
    __shared__ __align__(16) short As[2][64][72];
    __shared__ __align__(16) short Bs[2][64][72];
    const int bid = blockIdx.x;                       // 628 = 4*157
    GSrc s1 = {deep, MM, Lo_w, MM, 8, MM};
    GSrc s2 = {nullptr, 0, nullptr, 0, 0, 0};
    gemm_body(bid & 3, bid >> 2, 0, 4, s1, s2,
              out, KK, KK, 8, Lo_b, As, Bs);
}

extern "C" void kernel_launch(void* const* d_in, const int* in_sizes, int n_in,
                              void* d_out, int out_size, void* d_ws, size_t ws_size,
                              hipStream_t stream)
{
    const float* a_i     = (const float*)d_in[0];
    const float* inp     = (const float*)d_in[1];
    const float* hn_prev = (const float*)d_in[2];
    const float* cn_prev = (const float*)d_in[3];
    const float* f_att_w = (const float*)d_in[4];
    const float* f_att_b = (const float*)d_in[5];
    const float* gate_w  = (const float*)d_in[6];
    const float* gate_b  = (const float*)d_in[7];
    const float* E_w     = (const float*)d_in[8];
    const float* E_b     = (const float*)d_in[9];
    const float* W_ih    = (const float*)d_in[10];
    const float* W_hh    = (const float*)d_in[11];
    const float* b_ih    = (const float*)d_in[12];
    const float* b_hh    = (const float*)d_in[13];
    const float* Lh_w    = (const float*)d_in[14];
    const float* Lh_b    = (const float*)d_in[15];
    const float* Lz_w    = (const float*)d_in[16];
    const float* Lz_b    = (const float*)d_in[17];
    const float* Lo_w    = (const float*)d_in[18];
    const float* Lo_b    = (const float*)d_in[19];

    float* out = (float*)d_out;
    float* ws  = (float*)d_ws;

    float* PE     = ws + OFF_PE;
    float* BETA   = ws + OFF_BETA;
    float* Z      = ws + OFF_Z;
    float* EMB    = ws + OFF_EMB;
    float* DEEP   = ws + OFF_DEEP;
    float* EMBP   = ws + OFF_EMBP;
    float* GATESP = ws + OFF_GATESP;
    float* DP     = ws + OFF_DP;

    // L1: attention e-partials (global_load_lds slabs)
    att_e_slab<<<4096, 256, 0, stream>>>(a_i, f_att_w, PE);

    // L2: emb GEMM || gates_h GEMM
    l2_emb_gatesh<<<2048, 256, 0, stream>>>(inp, E_w, EMBP,
                                            hn_prev, W_ih, W_hh, GATESP);

    // L3: softmax+beta || emb reduce
    l3_softmax_embred<<<768, 256, 0, stream>>>(PE, hn_prev, f_att_w, f_att_b,
                                               gate_w, gate_b, out + OUT_AL, BETA,
                                               EMBP, E_b, EMB);

    // L4: attention z (slabs, a_i L3-resident)
    att_z_slab<<<4096, 256, 0, stream>>>(a_i, out + OUT_AL, BETA, Z);

    // L5: gates_e || gates_z || lz
    l5_gatesez_lz<<<1280, 256, 0, stream>>>(EMB, Z, W_ih, GATESP, Lz_w, DP);

    // L6: LSTM cell
    l6_lstm<<<1024, 256, 0, stream>>>(GATESP, b_ih, b_hh, cn_prev,
                                      out + OUT_HN, out + OUT_CN);

    // L7: hn@Lh_w^T (dp slices 8..23)
    l7_lh<<<512, 256, 0, stream>>>(out + OUT_HN, Lh_w,
                                   DP + (size_t)8 * BB * 512);

    // L8: deep = emb + sum(dp) + biases
    l8_deep<<<512, 256, 0, stream>>>(EMB, DP, Lh_b, Lz_b, DEEP);

    // L9: p_yt = deep @ Lo_w^T + Lo_b
    l9_pyt<<<628, 256, 0, stream>>>(DEEP, Lo_w, Lo_b, out + OUT_PY);
}

// Round 12
// 138.477 us; speedup vs baseline: 1.1919x; 1.1317x over previous
//
#include <hip/hip_runtime.h>
#include <hip/hip_bf16.h>
#include <math.h>

// Problem constants
#define BB 256
#define DD 512
#define LL 196
#define NN 1024
#define MM 512
#define KK 10000

// ---- output layout (float offsets) ----
#define OUT_PY 0
#define OUT_HN ((size_t)2560000)
#define OUT_CN ((size_t)2822144)
#define OUT_AL ((size_t)3084288)

// ---- workspace layout (float-word offsets) ----
#define OFF_PE     ((size_t)0)          // B*16*196 = 802816
#define OFF_BETA   ((size_t)802816)     // 256
#define OFF_EMB    ((size_t)803072)     // B*512 fp32 = 131072
#define OFF_EMBP   ((size_t)934144)     // 16 * B*512 = 2097152
#define OFF_GATESP ((size_t)3031296)    // 8 * B*4096 = 8388608
#define OFF_DP     ((size_t)11419904)   // 24 * B*512 = 3145728
// bf16 buffers (sizes in float-words = shorts/2)
#define OFF_EWB    ((size_t)14565632)   // 512*10000  -> 2560000
#define OFF_WIHB   ((size_t)17125632)   // 4096*2048  -> 4194304
#define OFF_WHHB   ((size_t)21319936)   // 4096*1024  -> 2097152
#define OFF_LHB    ((size_t)23417088)   // 512*1024   -> 262144
#define OFF_LZB    ((size_t)23679232)   // 512*512    -> 131072
#define OFF_LOB    ((size_t)23810304)   // 10000*512  -> 2560000
#define OFF_INPB   ((size_t)26370304)   // 256*10000  -> 1280000
#define OFF_HB     ((size_t)27650304)   // 256*1024   -> 131072
#define OFF_ZB     ((size_t)27781376)   // 256*512    -> 65536
#define OFF_EMBB   ((size_t)27846912)   // 256*512    -> 65536
#define OFF_DEEPB  ((size_t)27912448)   // 256*512    -> 65536
#define OFF_HNB    ((size_t)27977984)   // 256*1024   -> 131072
// end 28109056 floats = 112.4 MB

typedef __attribute__((ext_vector_type(8))) short short8v;
typedef __attribute__((ext_vector_type(4))) float f32x4;

__device__ __forceinline__ unsigned short f2bf(float f) {
    unsigned int u = __builtin_bit_cast(unsigned int, f);
    u += 0x7fffu + ((u >> 16) & 1u);            // RNE
    return (unsigned short)(u >> 16);
}

// fire-and-forget 16B global->LDS copy (no VGPR round-trip)
__device__ __forceinline__ void gl_lds16(const float* g, float* l) {
    __builtin_amdgcn_global_load_lds(
        (const __attribute__((address_space(1))) void*)g,
        (__attribute__((address_space(3))) void*)l, 16, 0, 0);
}

// load 8 k-contiguous bf16 (guarded) from pre-converted buffer
__device__ __forceinline__ short8v stage8b(const unsigned short* __restrict__ p,
                                           bool ok, int kbase, int Ktot) {
    if (ok && (kbase + 7 < Ktot)) return *(const short8v*)(p + kbase);
    short8v v;
#pragma unroll
    for (int i = 0; i < 8; ++i) {
        const int k = kbase + i;
        v[i] = (ok && k < Ktot) ? (short)p[k] : (short)0;
    }
    return v;
}

struct GSrc { const unsigned short* A; int lda; const unsigned short* B; int ldb; int ktn; int K; };

// Dual-source TN GEMM body, pure bf16 inputs (pre-converted), 64x64 tile,
// BK=64, 256 threads, 1-deep register prefetch.
__device__ __forceinline__ void gemm_body(
    const int bx, const int by, const int bz, const int rowBlocks,
    const GSrc s1, const GSrc s2,
    float* __restrict__ C, const int ldc, const int Ncols,
    const int ktPerSplit, const float* __restrict__ bias,
    short (*As)[64][72], short (*Bs)[64][72])
{
    const int t = threadIdx.x;
    const int row0 = bx * 64;
    const int col0 = by * 64;
    const int ktTot = s1.ktn + s2.ktn;
    const int kt0 = bz * ktPerSplit;
    const int nk = min(ktTot, kt0 + ktPerSplit) - kt0;

    const int sr = t >> 2;
    const int sk = (t & 3) << 4;
    const int bc = col0 + sr;
    const bool bok = (bc < Ncols);
    const unsigned short* aP1 = s1.A + (size_t)(row0 + sr) * s1.lda;
    const unsigned short* bP1 = s1.B + (size_t)(bok ? bc : 0) * s1.ldb;
    const unsigned short* aP2 = s2.A ? (s2.A + (size_t)(row0 + sr) * s2.lda) : aP1;
    const unsigned short* bP2 = s2.A ? (s2.B + (size_t)(bok ? bc : 0) * s2.ldb) : bP1;

    const int l = t & 63, w = t >> 6;
    const int wrow = (w >> 1) * 32, wcol = (w & 1) * 32;
    const int lr = l & 15, g = l >> 4, g8 = g * 8;

    f32x4 acc[2][2] = {};

    short8v sa0, sa1, sb0, sb1;
    {
        const int ktg = kt0;
        const unsigned short* aR; const unsigned short* bR; int kk, Kt;
        if (ktg < s1.ktn) { aR = aP1; bR = bP1; kk = (ktg << 6) + sk; Kt = s1.K; }
        else              { aR = aP2; bR = bP2; kk = ((ktg - s1.ktn) << 6) + sk; Kt = s2.K; }
        sa0 = stage8b(aR, true, kk, Kt);  sa1 = stage8b(aR, true, kk + 8, Kt);
        sb0 = stage8b(bR, bok,  kk, Kt);  sb1 = stage8b(bR, bok,  kk + 8, Kt);
    }
    *(short8v*)&As[0][sr][sk] = sa0; *(short8v*)&As[0][sr][sk + 8] = sa1;
    *(short8v*)&Bs[0][sr][sk] = sb0; *(short8v*)&Bs[0][sr][sk + 8] = sb1;
    __syncthreads();

    int cur = 0;
    for (int kt = 0; kt < nk; ++kt) {
        const bool more = (kt + 1 < nk);
        if (more) {
            const int ktg = kt0 + kt + 1;
            const unsigned short* aR; const unsigned short* bR; int kk, Kt;
            if (ktg < s1.ktn) { aR = aP1; bR = bP1; kk = (ktg << 6) + sk; Kt = s1.K; }
            else              { aR = aP2; bR = bP2; kk = ((ktg - s1.ktn) << 6) + sk; Kt = s2.K; }
            sa0 = stage8b(aR, true, kk, Kt);  sa1 = stage8b(aR, true, kk + 8, Kt);
            sb0 = stage8b(bR, bok,  kk, Kt);  sb1 = stage8b(bR, bok,  kk + 8, Kt);
        }
#pragma unroll
        for (int ks = 0; ks < 2; ++ks) {
            const int ko = ks * 32 + g8;
            short8v a0 = *(const short8v*)&As[cur][wrow + lr][ko];
            short8v a1 = *(const short8v*)&As[cur][wrow + 16 + lr][ko];
            short8v b0 = *(const short8v*)&Bs[cur][wcol + lr][ko];
            short8v b1 = *(const short8v*)&Bs[cur][wcol + 16 + lr][ko];
            acc[0][0] = __builtin_amdgcn_mfma_f32_16x16x32_bf16(a0, b0, acc[0][0], 0, 0, 0);
            acc[0][1] = __builtin_amdgcn_mfma_f32_16x16x32_bf16(a0, b1, acc[0][1], 0, 0, 0);
            acc[1][0] = __builtin_amdgcn_mfma_f32_16x16x32_bf16(a1, b0, acc[1][0], 0, 0, 0);
            acc[1][1] = __builtin_amdgcn_mfma_f32_16x16x32_bf16(a1, b1, acc[1][1], 0, 0, 0);
        }
        if (more) {
            *(short8v*)&As[cur ^ 1][sr][sk] = sa0;
            *(short8v*)&As[cur ^ 1][sr][sk + 8] = sa1;
            *(short8v*)&Bs[cur ^ 1][sr][sk] = sb0;
            *(short8v*)&Bs[cur ^ 1][sr][sk + 8] = sb1;
        }
        __syncthreads();
        cur ^= 1;
    }

    float* Cp = C + (size_t)bz * ((size_t)rowBlocks * 64) * ldc;
#pragma unroll
    for (int m = 0; m < 2; ++m)
#pragma unroll
        for (int n = 0; n < 2; ++n)
#pragma unroll
            for (int j = 0; j < 4; ++j) {
                const int r = row0 + wrow + m * 16 + g * 4 + j;
                const int c = col0 + wcol + n * 16 + lr;
                if (c < Ncols) {
                    float v = acc[m][n][j];
                    if (bias) v += bias[c];
                    Cp[(size_t)r * ldc + c] = v;
                }
            }
}

// ==== L1: att_e slabs (4096) || bf16 conversion of weights+inp+h (1615) ====
#define CVT_NBLK 1615
__global__ __launch_bounds__(256) void l1_atte_cvt(
    const float* __restrict__ a_i, const float* __restrict__ f_att_w,
    float* __restrict__ pe,
    const float* __restrict__ E_w, const float* __restrict__ W_ih,
    const float* __restrict__ W_hh, const float* __restrict__ Lh_w,
    const float* __restrict__ Lz_w, const float* __restrict__ Lo_w,
    const float* __restrict__ inp, const float* __restrict__ h,
    unsigned short* __restrict__ ewb, unsigned short* __restrict__ wihb,
    unsigned short* __restrict__ whhb, unsigned short* __restrict__ lhb,
    unsigned short* __restrict__ lzb, unsigned short* __restrict__ lob,
    unsigned short* __restrict__ inpb, unsigned short* __restrict__ hb)
{
    __shared__ __align__(16) float slab[6280];
    const int bid = blockIdx.x;
    const int t = threadIdx.x;

    if (bid < 4096) {
        const int b = bid >> 4, ch = bid & 15;
        const int w = t >> 6, lane = t & 63;
        const float* gbase = a_i + ((size_t)b * DD + ch * 32) * LL;
#pragma unroll
        for (int k = 0; k < 7; ++k) {
            const int cw = k * 256 + w * 64;
            if (cw + lane < 1568)
                gl_lds16(gbase + (size_t)(cw + lane) * 4, slab + (size_t)cw * 4);
        }
        if (t < 8) slab[6272 + t] = 0.f;
        asm volatile("s_waitcnt vmcnt(0)" ::: "memory");
        __syncthreads();
        if (t < LL) {
            const float* wp = f_att_w + ch * 32;
            float e = 0.f;
#pragma unroll
            for (int d = 0; d < 32; ++d) e += slab[d * LL + t] * wp[d];
            pe[((size_t)b * 16 + ch) * LL + t] = e;
        }
    } else {
        int lb = bid - 4096;
        const float* src; unsigned short* dst; int n;
        if      (lb < 313)  {             src = E_w;  dst = ewb;  n = 5120000; }
        else if (lb < 825)  { lb -= 313;  src = W_ih; dst = wihb; n = 8388608; }
        else if (lb < 1081) { lb -= 825;  src = W_hh; dst = whhb; n = 4194304; }
        else if (lb < 1113) { lb -= 1081; src = Lh_w; dst = lhb;  n = 524288; }
        else if (lb < 1129) { lb -= 1113; src = Lz_w; dst = lzb;  n = 262144; }
        else if (lb < 1442) { lb -= 1129; src = Lo_w; dst = lob;  n = 5120000; }
        else if (lb < 1599) { lb -= 1442; src = inp;  dst = inpb; n = 2560000; }
        else                { lb -= 1599; src = h;    dst = hb;   n = 262144; }
#pragma unroll
        for (int i = 0; i < 8; ++i) {
            const size_t e = (size_t)lb * 16384 + (size_t)i * 2048 + (size_t)t * 8;
            if (e + 8 <= (size_t)n) {
                const float4 x = *(const float4*)(src + e);
                const float4 y = *(const float4*)(src + e + 4);
                short8v v;
                v[0] = (short)f2bf(x.x); v[1] = (short)f2bf(x.y);
                v[2] = (short)f2bf(x.z); v[3] = (short)f2bf(x.w);
                v[4] = (short)f2bf(y.x); v[5] = (short)f2bf(y.y);
                v[6] = (short)f2bf(y.z); v[7] = (short)f2bf(y.w);
                *(short8v*)(dst + e) = v;
            }
        }
    }
}

// ==== L2: emb GEMM (512) || gates_h GEMM (1024) — bf16 sources ====
__global__ __launch_bounds__(256) void l2_emb_gatesh(
    const unsigned short* __restrict__ inpb, const unsigned short* __restrict__ ewb,
    float* __restrict__ embp,
    const unsigned short* __restrict__ hb, const unsigned short* __restrict__ wihb,
    const unsigned short* __restrict__ whhb, float* __restrict__ gatesp)
{
    __shared__ __align__(16) short As[2][64][72];
    __shared__ __align__(16) short Bs[2][64][72];
    const int bid = blockIdx.x;
    if (bid < 512) {                                  // 4*8*16, nk<=10
        GSrc s1 = {inpb, KK, ewb, KK, 157, KK};
        GSrc s2 = {nullptr, 0, nullptr, 0, 0, 0};
        gemm_body(bid & 3, (bid >> 2) & 7, bid >> 5, 4, s1, s2,
                  embp, MM, MM, 10, nullptr, As, Bs);
    } else {
        const int i = bid - 512;                      // 1024 = 4*64*4, nk=8
        GSrc s1 = {hb, NN, wihb + 512, 2048, 16, NN};
        GSrc s2 = {hb, NN, whhb, NN, 16, NN};
        gemm_body(i & 3, (i >> 2) & 63, i >> 8, 4, s1, s2,
                  gatesp, 4096, 4096, 8, nullptr, As, Bs);
    }
}

// ==== L3: softmax+beta (256) || emb reduce -> fp32 + bf16 (512) ====
__global__ __launch_bounds__(256) void l3_softmax_embred(
    const float* __restrict__ pe, const float* __restrict__ h,
    const float* __restrict__ f_att_w, const float* __restrict__ f_att_b,
    const float* __restrict__ gate_w, const float* __restrict__ gate_b,
    float* __restrict__ alpha_out, float* __restrict__ beta,
    const float* __restrict__ embp, const float* __restrict__ E_b,
    float* __restrict__ emb, unsigned short* __restrict__ embb)
{
    const int bid = blockIdx.x;
    const int t = threadIdx.x;
    if (bid < 256) {
        const int b = bid;
        __shared__ float red[256];
        __shared__ float red2[256];
        const float4 h4 = *(const float4*)(h + (size_t)b * NN + t * 4);
        const float4 w4 = *(const float4*)(f_att_w + DD + t * 4);
        const float4 g4 = *(const float4*)(gate_w + t * 4);
        float hd = h4.x * w4.x + h4.y * w4.y + h4.z * w4.z + h4.w * w4.w;
        float gd = h4.x * g4.x + h4.y * g4.y + h4.z * g4.z + h4.w * g4.w;
        red[t] = hd; red2[t] = gd;
        __syncthreads();
        for (int s = 128; s > 0; s >>= 1) {
            if (t < s) { red[t] += red[t + s]; red2[t] += red2[t + s]; }
            __syncthreads();
        }
        const float hdot = red[0];
        const float gdot = red2[0];
        __syncthreads();
        float e = -3.4e38f;
        if (t < LL) {
            const float* p = pe + (size_t)b * 16 * LL + t;
            e = hdot + f_att_b[0];
#pragma unroll
            for (int ch = 0; ch < 16; ++ch) e += p[ch * LL];
        }
        red[t] = e;
        __syncthreads();
        for (int s = 128; s > 0; s >>= 1) {
            if (t < s) red[t] = fmaxf(red[t], red[t + s]);
            __syncthreads();
        }
        const float mx = red[0];
        __syncthreads();
        const float ex = (t < LL) ? expf(e - mx) : 0.f;
        red[t] = ex;
        __syncthreads();
        for (int s = 128; s > 0; s >>= 1) {
            if (t < s) red[t] += red[t + s];
            __syncthreads();
        }
        const float inv = 1.f / red[0];
        if (t < LL) alpha_out[(size_t)b * LL + t] = ex * inv;
        if (t == 0) beta[b] = 1.f / (1.f + expf(-(gdot + gate_b[0])));
    } else {
        const int idx = (bid - 256) * 256 + t;        // < B*512
        const int j = idx & 511;
        float v = E_b[j];
#pragma unroll
        for (int s = 0; s < 16; ++s) v += embp[(size_t)s * (BB * 512) + idx];
        emb[idx] = v;
        embb[idx] = f2bf(v);
    }
}

// ==== L4: att_z slabs (4096) -> z bf16 (a_i L3-resident) ====
__global__ __launch_bounds__(256) void l4_attz(
    const float* __restrict__ a_i, const float* __restrict__ alpha,
    const float* __restrict__ beta, unsigned short* __restrict__ zb)
{
    __shared__ __align__(16) float slab[6280];
    __shared__ float al[200];
    const int t = threadIdx.x;
    const int b = blockIdx.x >> 4, ch = blockIdx.x & 15;
    const int w = t >> 6, lane = t & 63;
    const float* gbase = a_i + ((size_t)b * DD + ch * 32) * LL;
#pragma unroll
    for (int k = 0; k < 7; ++k) {
        const int cw = k * 256 + w * 64;
        if (cw + lane < 1568)
            gl_lds16(gbase + (size_t)(cw + lane) * 4, slab + (size_t)cw * 4);
    }
    if (t < 200) al[t] = (t < LL) ? alpha[(size_t)b * LL + t] : 0.f;
    if (t < 8) slab[6272 + t] = 0.f;
    asm volatile("s_waitcnt vmcnt(0)" ::: "memory");
    __syncthreads();
    const int r = t >> 3, q = t & 7;
    const float* rowp = slab + r * LL + q * 25;
    const float* alq  = al + q * 25;
    float s = 0.f;
#pragma unroll
    for (int j = 0; j < 25; ++j) s += rowp[j] * alq[j];
    s += __shfl_xor(s, 1, 64);
    s += __shfl_xor(s, 2, 64);
    s += __shfl_xor(s, 4, 64);
    if (q == 0) zb[(size_t)b * DD + ch * 32 + r] = f2bf(beta[b] * s);
}

// ==== L5: gates_e (512) || gates_z (512) || lz (256) ====
__global__ __launch_bounds__(256) void l5_gatesez_lz(
    const unsigned short* __restrict__ embb, const unsigned short* __restrict__ zb,
    const unsigned short* __restrict__ wihb, float* __restrict__ gatesp,
    const unsigned short* __restrict__ lzb, float* __restrict__ dp)
{
    __shared__ __align__(16) short As[2][64][72];
    __shared__ __align__(16) short Bs[2][64][72];
    const int bid = blockIdx.x;
    if (bid < 512) {                                  // 4*64*2 -> slices 4..5
        GSrc s1 = {embb, MM, wihb, 2048, 8, MM};
        GSrc s2 = {nullptr, 0, nullptr, 0, 0, 0};
        gemm_body(bid & 3, (bid >> 2) & 63, bid >> 8, 4, s1, s2,
                  gatesp + (size_t)4 * BB * 4096, 4096, 4096, 4, nullptr, As, Bs);
    } else if (bid < 1024) {                          // slices 6..7
        const int i = bid - 512;
        GSrc s1 = {zb, DD, wihb + 1536, 2048, 8, DD};
        GSrc s2 = {nullptr, 0, nullptr, 0, 0, 0};
        gemm_body(i & 3, (i >> 2) & 63, i >> 8, 4, s1, s2,
                  gatesp + (size_t)6 * BB * 4096, 4096, 4096, 4, nullptr, As, Bs);
    } else {
        const int i = bid - 1024;                     // 256 = 4*8*8 -> dp 0..7
        GSrc s1 = {zb, DD, lzb, DD, 8, DD};
        GSrc s2 = {nullptr, 0, nullptr, 0, 0, 0};
        gemm_body(i & 3, (i >> 2) & 7, i >> 5, 4, s1, s2,
                  dp, MM, MM, 1, nullptr, As, Bs);
    }
}

// ==== L6: LSTM cell -> hn fp32 + bf16 ====
__global__ __launch_bounds__(256) void l6_lstm(
    const float* __restrict__ gatesp,
    const float* __restrict__ b_ih, const float* __restrict__ b_hh,
    const float* __restrict__ c_prev, float* __restrict__ hn, float* __restrict__ cn,
    unsigned short* __restrict__ hnb)
{
    const int idx = blockIdx.x * 256 + threadIdx.x;   // < B*1024
    const int b = idx >> 10, n = idx & 1023;
    float g[4];
#pragma unroll
    for (int gi = 0; gi < 4; ++gi) {
        const int col = gi * 1024 + n;
        const size_t o = (size_t)b * 4096 + col;
        float v = b_ih[col] + b_hh[col];
#pragma unroll
        for (int s = 0; s < 8; ++s) v += gatesp[(size_t)s * (BB * 4096) + o];
        g[gi] = v;
    }
    const float si = 1.f / (1.f + expf(-g[0]));
    const float sf = 1.f / (1.f + expf(-g[1]));
    const float so = 1.f / (1.f + expf(-g[3]));
    const float tg = tanhf(g[2]);
    const float c = c_prev[idx];
    const float cnv = sf * c + si * tg;
    const float hnv = so * tanhf(cnv);
    cn[idx] = cnv;
    hn[idx] = hnv;
    hnb[idx] = f2bf(hnv);
}

// ==== L7: lh GEMM (512, dp slices 8..23) ====
__global__ __launch_bounds__(256) void l7_lh(
    const unsigned short* __restrict__ hnb, const unsigned short* __restrict__ lhb,
    float* __restrict__ dp_hi)
{
    __shared__ __align__(16) short As[2][64][72];
    __shared__ __align__(16) short Bs[2][64][72];
    const int bid = blockIdx.x;                       // 512 = 4*8*16
    GSrc s1 = {hnb, NN, lhb, NN, 16, NN};
    GSrc s2 = {nullptr, 0, nullptr, 0, 0, 0};
    gemm_body(bid & 3, (bid >> 2) & 7, bid >> 5, 4, s1, s2,
              dp_hi, MM, MM, 1, nullptr, As, Bs);
}

// ==== L8: build deep -> bf16 ====
__global__ __launch_bounds__(256) void l8_deep(
    const float* __restrict__ emb, const float* __restrict__ dp,
    const float* __restrict__ Lh_b, const float* __restrict__ Lz_b,
    unsigned short* __restrict__ deepb)
{
    const int idx = blockIdx.x * 256 + threadIdx.x;   // < B*512
    const int j = idx & 511;
    float v = emb[idx] + Lh_b[j] + Lz_b[j];
#pragma unroll
    for (int s = 0; s < 24; ++s) v += dp[(size_t)s * (BB * 512) + idx];
    deepb[idx] = f2bf(v);
}

// ==== L9: p_yt GEMM (628) ====
__global__ __launch_bounds__(256) void l9_pyt(
    const unsigned short* __restrict__ deepb, const unsigned short* __restrict__ lob,
    const float* __restrict__ Lo_b, float* __restrict__ out)
{
    __shared__ __align__(16) short As[2][64][72];
    __shared__ __align__(16) short Bs[2][64][72];
    const int bid = blockIdx.x;                       // 628 = 4*157
    GSrc s1 = {deepb, MM, lob, MM, 8, MM};
    GSrc s2 = {nullptr, 0, nullptr, 0, 0, 0};
    gemm_body(bid & 3, bid >> 2, 0, 4, s1, s2,
              out, KK, KK, 8, Lo_b, As, Bs);
}

extern "C" void kernel_launch(void* const* d_in, const int* in_sizes, int n_in,
                              void* d_out, int out_size, void* d_ws, size_t ws_size,
                              hipStream_t stream)
{
    const float* a_i     = (const float*)d_in[0];
    const float* inp     = (const float*)d_in[1];
    const float* hn_prev = (const float*)d_in[2];
    const float* cn_prev = (const float*)d_in[3];
    const float* f_att_w = (const float*)d_in[4];
    const float* f_att_b = (const float*)d_in[5];
    const float* gate_w  = (const float*)d_in[6];
    const float* gate_b  = (const float*)d_in[7];
    const float* E_w     = (const float*)d_in[8];
    const float* E_b     = (const float*)d_in[9];
    const float* W_ih    = (const float*)d_in[10];
    const float* W_hh    = (const float*)d_in[11];
    const float* b_ih    = (const float*)d_in[12];
    const float* b_hh    = (const float*)d_in[13];
    const float* Lh_w    = (const float*)d_in[14];
    const float* Lh_b    = (const float*)d_in[15];
    const float* Lz_w    = (const float*)d_in[16];
    const float* Lz_b    = (const float*)d_in[17];
    const float* Lo_w    = (const float*)d_in[18];
    const float* Lo_b    = (const float*)d_in[19];

    float* out = (float*)d_out;
    float* ws  = (float*)d_ws;

    float* PE     = ws + OFF_PE;
    float* BETA   = ws + OFF_BETA;
    float* EMB    = ws + OFF_EMB;
    float* EMBP   = ws + OFF_EMBP;
    float* GATESP = ws + OFF_GATESP;
    float* DP     = ws + OFF_DP;
    unsigned short* EWB   = (unsigned short*)(ws + OFF_EWB);
    unsigned short* WIHB  = (unsigned short*)(ws + OFF_WIHB);
    unsigned short* WHHB  = (unsigned short*)(ws + OFF_WHHB);
    unsigned short* LHB   = (unsigned short*)(ws + OFF_LHB);
    unsigned short* LZB   = (unsigned short*)(ws + OFF_LZB);
    unsigned short* LOB   = (unsigned short*)(ws + OFF_LOB);
    unsigned short* INPB  = (unsigned short*)(ws + OFF_INPB);
    unsigned short* HB    = (unsigned short*)(ws + OFF_HB);
    unsigned short* ZB    = (unsigned short*)(ws + OFF_ZB);
    unsigned short* EMBB  = (unsigned short*)(ws + OFF_EMBB);
    unsigned short* DEEPB = (unsigned short*)(ws + OFF_DEEPB);
    unsigned short* HNB   = (unsigned short*)(ws + OFF_HNB);

    // L1: attention e-partials || bf16 conversion of weights + inp + h
    l1_atte_cvt<<<4096 + CVT_NBLK, 256, 0, stream>>>(
        a_i, f_att_w, PE,
        E_w, W_ih, W_hh, Lh_w, Lz_w, Lo_w, inp, hn_prev,
        EWB, WIHB, WHHB, LHB, LZB, LOB, INPB, HB);

    // L2: emb GEMM || gates_h GEMM (bf16)
    l2_emb_gatesh<<<1536, 256, 0, stream>>>(INPB, EWB, EMBP,
                                            HB, WIHB, WHHB, GATESP);

    // L3: softmax+beta || emb reduce (fp32 + bf16)
    l3_softmax_embred<<<768, 256, 0, stream>>>(PE, hn_prev, f_att_w, f_att_b,
                                               gate_w, gate_b, out + OUT_AL, BETA,
                                               EMBP, E_b, EMB, EMBB);

    // L4: attention z -> bf16 (a_i L3-resident)
    l4_attz<<<4096, 256, 0, stream>>>(a_i, out + OUT_AL, BETA, ZB);

    // L5: gates_e || gates_z || lz (bf16)
    l5_gatesez_lz<<<1280, 256, 0, stream>>>(EMBB, ZB, WIHB, GATESP, LZB, DP);

    // L6: LSTM cell
    l6_lstm<<<1024, 256, 0, stream>>>(GATESP, b_ih, b_hh, cn_prev,
                                      out + OUT_HN, out + OUT_CN, HNB);

    // L7: hn@Lh_w^T (dp slices 8..23)
    l7_lh<<<512, 256, 0, stream>>>(HNB, LHB, DP + (size_t)8 * BB * 512);

    // L8: deep = emb + sum(dp) + biases -> bf16
    l8_deep<<<512, 256, 0, stream>>>(EMB, DP, Lh_b, Lz_b, DEEPB);

    // L9: p_yt = deep @ Lo_w^T + Lo_b
    l9_pyt<<<628, 256, 0, stream>>>(DEEPB, LOB, Lo_b, out + OUT_PY);
}

// Round 13
// 137.010 us; speedup vs baseline: 1.2047x; 1.0107x over previous
//
#include <hip/hip_runtime.h>
#include <hip/hip_bf16.h>
#include <math.h>

// Problem constants
#define BB 256
#define DD 512
#define LL 196
#define NN 1024
#define MM 512
#define KK 10000

// ---- output layout (float offsets) ----
#define OUT_PY 0
#define OUT_HN ((size_t)2560000)
#define OUT_CN ((size_t)2822144)
#define OUT_AL ((size_t)3084288)

// ---- workspace layout (float-word offsets) ----
#define OFF_PE     ((size_t)0)          // B*16*196 = 802816
#define OFF_BETA   ((size_t)802816)     // 256
#define OFF_EMB    ((size_t)803072)     // B*512 fp32 = 131072
#define OFF_EMBP   ((size_t)934144)     // 16 * B*512 = 2097152
#define OFF_GATESP ((size_t)3031296)    // 8 * B*4096 = 8388608
#define OFF_DP     ((size_t)11419904)   // 24 * B*512 = 3145728
// bf16 buffers (sizes in float-words = shorts/2)
#define OFF_EWB    ((size_t)14565632)   // 512*10000  -> 2560000
#define OFF_WIHB   ((size_t)17125632)   // 4096*2048  -> 4194304
#define OFF_WHHB   ((size_t)21319936)   // 4096*1024  -> 2097152
#define OFF_LHB    ((size_t)23417088)   // 512*1024   -> 262144
#define OFF_LZB    ((size_t)23679232)   // 512*512    -> 131072
#define OFF_LOB    ((size_t)23810304)   // 10000*512  -> 2560000
#define OFF_INPB   ((size_t)26370304)   // 256*10000  -> 1280000
#define OFF_HB     ((size_t)27650304)   // 256*1024   -> 131072
#define OFF_ZB     ((size_t)27781376)   // 256*512    -> 65536
#define OFF_EMBB   ((size_t)27846912)   // 256*512    -> 65536
#define OFF_DEEPB  ((size_t)27912448)   // 256*512    -> 65536
#define OFF_HNB    ((size_t)27977984)   // 256*1024   -> 131072
// end 28109056 floats = 112.4 MB

typedef __attribute__((ext_vector_type(8))) short short8v;
typedef __attribute__((ext_vector_type(4))) float f32x4;

__device__ __forceinline__ unsigned short f2bf(float f) {
    unsigned int u = __builtin_bit_cast(unsigned int, f);
    u += 0x7fffu + ((u >> 16) & 1u);            // RNE
    return (unsigned short)(u >> 16);
}

// fire-and-forget 16B global->LDS copy (no VGPR round-trip)
__device__ __forceinline__ void gl_lds16(const float* g, float* l) {
    __builtin_amdgcn_global_load_lds(
        (const __attribute__((address_space(1))) void*)g,
        (__attribute__((address_space(3))) void*)l, 16, 0, 0);
}

// bf16 conversion body: block lb converts 16384 elems of src -> dst
__device__ __forceinline__ void cvt_body(int lb, const float* __restrict__ src,
                                         unsigned short* __restrict__ dst, int n,
                                         int t) {
#pragma unroll
    for (int i = 0; i < 8; ++i) {
        const size_t e = (size_t)lb * 16384 + (size_t)i * 2048 + (size_t)t * 8;
        if (e + 8 <= (size_t)n) {
            const float4 x = *(const float4*)(src + e);
            const float4 y = *(const float4*)(src + e + 4);
            short8v v;
            v[0] = (short)f2bf(x.x); v[1] = (short)f2bf(x.y);
            v[2] = (short)f2bf(x.z); v[3] = (short)f2bf(x.w);
            v[4] = (short)f2bf(y.x); v[5] = (short)f2bf(y.y);
            v[6] = (short)f2bf(y.z); v[7] = (short)f2bf(y.w);
            *(short8v*)(dst + e) = v;
        }
    }
}

// load 8 k-contiguous bf16 (guarded) from pre-converted buffer
__device__ __forceinline__ short8v stage8b(const unsigned short* __restrict__ p,
                                           bool ok, int kbase, int Ktot) {
    if (ok && (kbase + 7 < Ktot)) return *(const short8v*)(p + kbase);
    short8v v;
#pragma unroll
    for (int i = 0; i < 8; ++i) {
        const int k = kbase + i;
        v[i] = (ok && k < Ktot) ? (short)p[k] : (short)0;
    }
    return v;
}

struct GSrc { const unsigned short* A; int lda; const unsigned short* B; int ldb; int ktn; int K; };

// Dual-source TN GEMM body, pure bf16 inputs, 64x64 tile, BK=64, 256 threads.
__device__ __forceinline__ void gemm_body(
    const int bx, const int by, const int bz, const int rowBlocks,
    const GSrc s1, const GSrc s2,
    float* __restrict__ C, const int ldc, const int Ncols,
    const int ktPerSplit, const float* __restrict__ bias,
    short (*As)[64][72], short (*Bs)[64][72])
{
    const int t = threadIdx.x;
    const int row0 = bx * 64;
    const int col0 = by * 64;
    const int ktTot = s1.ktn + s2.ktn;
    const int kt0 = bz * ktPerSplit;
    const int nk = min(ktTot, kt0 + ktPerSplit) - kt0;

    const int sr = t >> 2;
    const int sk = (t & 3) << 4;
    const int bc = col0 + sr;
    const bool bok = (bc < Ncols);
    const unsigned short* aP1 = s1.A + (size_t)(row0 + sr) * s1.lda;
    const unsigned short* bP1 = s1.B + (size_t)(bok ? bc : 0) * s1.ldb;
    const unsigned short* aP2 = s2.A ? (s2.A + (size_t)(row0 + sr) * s2.lda) : aP1;
    const unsigned short* bP2 = s2.A ? (s2.B + (size_t)(bok ? bc : 0) * s2.ldb) : bP1;

    const int l = t & 63, w = t >> 6;
    const int wrow = (w >> 1) * 32, wcol = (w & 1) * 32;
    const int lr = l & 15, g = l >> 4, g8 = g * 8;

    f32x4 acc[2][2] = {};

    short8v sa0, sa1, sb0, sb1;
    {
        const int ktg = kt0;
        const unsigned short* aR; const unsigned short* bR; int kk, Kt;
        if (ktg < s1.ktn) { aR = aP1; bR = bP1; kk = (ktg << 6) + sk; Kt = s1.K; }
        else              { aR = aP2; bR = bP2; kk = ((ktg - s1.ktn) << 6) + sk; Kt = s2.K; }
        sa0 = stage8b(aR, true, kk, Kt);  sa1 = stage8b(aR, true, kk + 8, Kt);
        sb0 = stage8b(bR, bok,  kk, Kt);  sb1 = stage8b(bR, bok,  kk + 8, Kt);
    }
    *(short8v*)&As[0][sr][sk] = sa0; *(short8v*)&As[0][sr][sk + 8] = sa1;
    *(short8v*)&Bs[0][sr][sk] = sb0; *(short8v*)&Bs[0][sr][sk + 8] = sb1;
    __syncthreads();

    int cur = 0;
    for (int kt = 0; kt < nk; ++kt) {
        const bool more = (kt + 1 < nk);
        if (more) {
            const int ktg = kt0 + kt + 1;
            const unsigned short* aR; const unsigned short* bR; int kk, Kt;
            if (ktg < s1.ktn) { aR = aP1; bR = bP1; kk = (ktg << 6) + sk; Kt = s1.K; }
            else              { aR = aP2; bR = bP2; kk = ((ktg - s1.ktn) << 6) + sk; Kt = s2.K; }
            sa0 = stage8b(aR, true, kk, Kt);  sa1 = stage8b(aR, true, kk + 8, Kt);
            sb0 = stage8b(bR, bok,  kk, Kt);  sb1 = stage8b(bR, bok,  kk + 8, Kt);
        }
#pragma unroll
        for (int ks = 0; ks < 2; ++ks) {
            const int ko = ks * 32 + g8;
            short8v a0 = *(const short8v*)&As[cur][wrow + lr][ko];
            short8v a1 = *(const short8v*)&As[cur][wrow + 16 + lr][ko];
            short8v b0 = *(const short8v*)&Bs[cur][wcol + lr][ko];
            short8v b1 = *(const short8v*)&Bs[cur][wcol + 16 + lr][ko];
            acc[0][0] = __builtin_amdgcn_mfma_f32_16x16x32_bf16(a0, b0, acc[0][0], 0, 0, 0);
            acc[0][1] = __builtin_amdgcn_mfma_f32_16x16x32_bf16(a0, b1, acc[0][1], 0, 0, 0);
            acc[1][0] = __builtin_amdgcn_mfma_f32_16x16x32_bf16(a1, b0, acc[1][0], 0, 0, 0);
            acc[1][1] = __builtin_amdgcn_mfma_f32_16x16x32_bf16(a1, b1, acc[1][1], 0, 0, 0);
        }
        if (more) {
            *(short8v*)&As[cur ^ 1][sr][sk] = sa0;
            *(short8v*)&As[cur ^ 1][sr][sk + 8] = sa1;
            *(short8v*)&Bs[cur ^ 1][sr][sk] = sb0;
            *(short8v*)&Bs[cur ^ 1][sr][sk + 8] = sb1;
        }
        __syncthreads();
        cur ^= 1;
    }

    float* Cp = C + (size_t)bz * ((size_t)rowBlocks * 64) * ldc;
#pragma unroll
    for (int m = 0; m < 2; ++m)
#pragma unroll
        for (int n = 0; n < 2; ++n)
#pragma unroll
            for (int j = 0; j < 4; ++j) {
                const int r = row0 + wrow + m * 16 + g * 4 + j;
                const int c = col0 + wcol + n * 16 + lr;
                if (c < Ncols) {
                    float v = acc[m][n][j];
                    if (bias) v += bias[c];
                    Cp[(size_t)r * ldc + c] = v;
                }
            }
}

// ==== M1: att_e slabs (4096) || cvt{E_w:313, inp:157, h:16} ====
__global__ __launch_bounds__(256) void m1_atte_cvt1(
    const float* __restrict__ a_i, const float* __restrict__ f_att_w,
    float* __restrict__ pe,
    const float* __restrict__ E_w, const float* __restrict__ inp,
    const float* __restrict__ h,
    unsigned short* __restrict__ ewb, unsigned short* __restrict__ inpb,
    unsigned short* __restrict__ hb)
{
    __shared__ __align__(16) float slab[6280];
    const int bid = blockIdx.x;
    const int t = threadIdx.x;

    if (bid < 4096) {
        const int b = bid >> 4, ch = bid & 15;
        const int w = t >> 6, lane = t & 63;
        const float* gbase = a_i + ((size_t)b * DD + ch * 32) * LL;
#pragma unroll
        for (int k = 0; k < 7; ++k) {
            const int cw = k * 256 + w * 64;
            if (cw + lane < 1568)
                gl_lds16(gbase + (size_t)(cw + lane) * 4, slab + (size_t)cw * 4);
        }
        if (t < 8) slab[6272 + t] = 0.f;
        asm volatile("s_waitcnt vmcnt(0)" ::: "memory");
        __syncthreads();
        if (t < LL) {
            const float* wp = f_att_w + ch * 32;
            float e = 0.f;
#pragma unroll
            for (int d = 0; d < 32; ++d) e += slab[d * LL + t] * wp[d];
            pe[((size_t)b * 16 + ch) * LL + t] = e;
        }
    } else {
        int lb = bid - 4096;
        if      (lb < 313) cvt_body(lb, E_w, ewb, 5120000, t);
        else if (lb < 470) cvt_body(lb - 313, inp, inpb, 2560000, t);
        else               cvt_body(lb - 470, h, hb, 262144, t);
    }
}

// ==== M2: softmax (256) || emb GEMM (512) || cvt{W_ih:512, W_hh:256} ====
__global__ __launch_bounds__(256) void m2_softmax_emb_cvt2(
    const float* __restrict__ pe, const float* __restrict__ h,
    const float* __restrict__ f_att_w, const float* __restrict__ f_att_b,
    const float* __restrict__ gate_w, const float* __restrict__ gate_b,
    float* __restrict__ alpha_out, float* __restrict__ beta,
    const unsigned short* __restrict__ inpb, const unsigned short* __restrict__ ewb,
    float* __restrict__ embp,
    const float* __restrict__ W_ih, const float* __restrict__ W_hh,
    unsigned short* __restrict__ wihb, unsigned short* __restrict__ whhb)
{
    __shared__ __align__(16) unsigned char smem[36864];
    const int bid = blockIdx.x;
    const int t = threadIdx.x;
    if (bid < 256) {
        const int b = bid;
        float* red  = (float*)smem;
        float* red2 = red + 256;
        const float4 h4 = *(const float4*)(h + (size_t)b * NN + t * 4);
        const float4 w4 = *(const float4*)(f_att_w + DD + t * 4);
        const float4 g4 = *(const float4*)(gate_w + t * 4);
        float hd = h4.x * w4.x + h4.y * w4.y + h4.z * w4.z + h4.w * w4.w;
        float gd = h4.x * g4.x + h4.y * g4.y + h4.z * g4.z + h4.w * g4.w;
        red[t] = hd; red2[t] = gd;
        __syncthreads();
        for (int s = 128; s > 0; s >>= 1) {
            if (t < s) { red[t] += red[t + s]; red2[t] += red2[t + s]; }
            __syncthreads();
        }
        const float hdot = red[0];
        const float gdot = red2[0];
        __syncthreads();
        float e = -3.4e38f;
        if (t < LL) {
            const float* p = pe + (size_t)b * 16 * LL + t;
            e = hdot + f_att_b[0];
#pragma unroll
            for (int ch = 0; ch < 16; ++ch) e += p[ch * LL];
        }
        red[t] = e;
        __syncthreads();
        for (int s = 128; s > 0; s >>= 1) {
            if (t < s) red[t] = fmaxf(red[t], red[t + s]);
            __syncthreads();
        }
        const float mx = red[0];
        __syncthreads();
        const float ex = (t < LL) ? expf(e - mx) : 0.f;
        red[t] = ex;
        __syncthreads();
        for (int s = 128; s > 0; s >>= 1) {
            if (t < s) red[t] += red[t + s];
            __syncthreads();
        }
        const float inv = 1.f / red[0];
        if (t < LL) alpha_out[(size_t)b * LL + t] = ex * inv;
        if (t == 0) beta[b] = 1.f / (1.f + expf(-(gdot + gate_b[0])));
    } else if (bid < 768) {
        short (*As)[64][72] = (short (*)[64][72])smem;
        short (*Bs)[64][72] = (short (*)[64][72])(smem + 18432);
        const int i = bid - 256;                      // 512 = 4*8*16, nk<=10
        GSrc s1 = {inpb, KK, ewb, KK, 157, KK};
        GSrc s2 = {nullptr, 0, nullptr, 0, 0, 0};
        gemm_body(i & 3, (i >> 2) & 7, i >> 5, 4, s1, s2,
                  embp, MM, MM, 10, nullptr, As, Bs);
    } else {
        int lb = bid - 768;
        if (lb < 512) cvt_body(lb, W_ih, wihb, 8388608, t);
        else          cvt_body(lb - 512, W_hh, whhb, 4194304, t);
    }
}

// ==== M3: att_z slabs (4096) || emb reduce (512) || cvt{Lo:313,Lh:32,Lz:16} ====
__global__ __launch_bounds__(256) void m3_attz_embred_cvt3(
    const float* __restrict__ a_i, const float* __restrict__ alpha,
    const float* __restrict__ beta, unsigned short* __restrict__ zb,
    const float* __restrict__ embp, const float* __restrict__ E_b,
    float* __restrict__ emb, unsigned short* __restrict__ embb,
    const float* __restrict__ Lo_w, const float* __restrict__ Lh_w,
    const float* __restrict__ Lz_w,
    unsigned short* __restrict__ lob, unsigned short* __restrict__ lhb,
    unsigned short* __restrict__ lzb)
{
    __shared__ __align__(16) float slab[6280];
    __shared__ float al[200];
    const int bid = blockIdx.x;
    const int t = threadIdx.x;

    if (bid < 4096) {
        const int b = bid >> 4, ch = bid & 15;
        const int w = t >> 6, lane = t & 63;
        const float* gbase = a_i + ((size_t)b * DD + ch * 32) * LL;
#pragma unroll
        for (int k = 0; k < 7; ++k) {
            const int cw = k * 256 + w * 64;
            if (cw + lane < 1568)
                gl_lds16(gbase + (size_t)(cw + lane) * 4, slab + (size_t)cw * 4);
        }
        if (t < 200) al[t] = (t < LL) ? alpha[(size_t)b * LL + t] : 0.f;
        if (t < 8) slab[6272 + t] = 0.f;
        asm volatile("s_waitcnt vmcnt(0)" ::: "memory");
        __syncthreads();
        const int r = t >> 3, q = t & 7;
        const float* rowp = slab + r * LL + q * 25;
        const float* alq  = al + q * 25;
        float s = 0.f;
#pragma unroll
        for (int j = 0; j < 25; ++j) s += rowp[j] * alq[j];
        s += __shfl_xor(s, 1, 64);
        s += __shfl_xor(s, 2, 64);
        s += __shfl_xor(s, 4, 64);
        if (q == 0) zb[(size_t)b * DD + ch * 32 + r] = f2bf(beta[b] * s);
    } else if (bid < 4608) {
        const int idx = (bid - 4096) * 256 + t;       // < B*512
        const int j = idx & 511;
        float v = E_b[j];
#pragma unroll
        for (int s = 0; s < 16; ++s) v += embp[(size_t)s * (BB * 512) + idx];
        emb[idx] = v;
        embb[idx] = f2bf(v);
    } else {
        int lb = bid - 4608;
        if      (lb < 313) cvt_body(lb, Lo_w, lob, 5120000, t);
        else if (lb < 345) cvt_body(lb - 313, Lh_w, lhb, 524288, t);
        else               cvt_body(lb - 345, Lz_w, lzb, 262144, t);
    }
}

// ==== M4: gates_h (1024) || gates_e (512) || gates_z (512) || lz (256) ====
__global__ __launch_bounds__(256) void m4_gates_lz(
    const unsigned short* __restrict__ hb, const unsigned short* __restrict__ embb,
    const unsigned short* __restrict__ zb,
    const unsigned short* __restrict__ wihb, const unsigned short* __restrict__ whhb,
    float* __restrict__ gatesp,
    const unsigned short* __restrict__ lzb, float* __restrict__ dp)
{
    __shared__ __align__(16) unsigned char smem[36864];
    short (*As)[64][72] = (short (*)[64][72])smem;
    short (*Bs)[64][72] = (short (*)[64][72])(smem + 18432);
    const int bid = blockIdx.x;
    if (bid < 1024) {                                 // 4*64*4 -> slices 0..3
        GSrc s1 = {hb, NN, wihb + 512, 2048, 16, NN};
        GSrc s2 = {hb, NN, whhb, NN, 16, NN};
        gemm_body(bid & 3, (bid >> 2) & 63, bid >> 8, 4, s1, s2,
                  gatesp, 4096, 4096, 8, nullptr, As, Bs);
    } else if (bid < 1536) {                          // 4*64*2 -> slices 4..5
        const int i = bid - 1024;
        GSrc s1 = {embb, MM, wihb, 2048, 8, MM};
        GSrc s2 = {nullptr, 0, nullptr, 0, 0, 0};
        gemm_body(i & 3, (i >> 2) & 63, i >> 8, 4, s1, s2,
                  gatesp + (size_t)4 * BB * 4096, 4096, 4096, 4, nullptr, As, Bs);
    } else if (bid < 2048) {                          // slices 6..7
        const int i = bid - 1536;
        GSrc s1 = {zb, DD, wihb + 1536, 2048, 8, DD};
        GSrc s2 = {nullptr, 0, nullptr, 0, 0, 0};
        gemm_body(i & 3, (i >> 2) & 63, i >> 8, 4, s1, s2,
                  gatesp + (size_t)6 * BB * 4096, 4096, 4096, 4, nullptr, As, Bs);
    } else {
        const int i = bid - 2048;                     // 256 = 4*8*8 -> dp 0..7
        GSrc s1 = {zb, DD, lzb, DD, 8, DD};
        GSrc s2 = {nullptr, 0, nullptr, 0, 0, 0};
        gemm_body(i & 3, (i >> 2) & 7, i >> 5, 4, s1, s2,
                  dp, MM, MM, 1, nullptr, As, Bs);
    }
}

// ==== M5: LSTM cell (sums 8 gate slices) -> hn fp32 + bf16 ====
__global__ __launch_bounds__(256) void m5_lstm(
    const float* __restrict__ gatesp,
    const float* __restrict__ b_ih, const float* __restrict__ b_hh,
    const float* __restrict__ c_prev, float* __restrict__ hn, float* __restrict__ cn,
    unsigned short* __restrict__ hnb)
{
    const int idx = blockIdx.x * 256 + threadIdx.x;   // < B*1024
    const int b = idx >> 10, n = idx & 1023;
    float g[4];
#pragma unroll
    for (int gi = 0; gi < 4; ++gi) {
        const int col = gi * 1024 + n;
        const size_t o = (size_t)b * 4096 + col;
        float v = b_ih[col] + b_hh[col];
#pragma unroll
        for (int s = 0; s < 8; ++s) v += gatesp[(size_t)s * (BB * 4096) + o];
        g[gi] = v;
    }
    const float si = 1.f / (1.f + expf(-g[0]));
    const float sf = 1.f / (1.f + expf(-g[1]));
    const float so = 1.f / (1.f + expf(-g[3]));
    const float tg = tanhf(g[2]);
    const float c = c_prev[idx];
    const float cnv = sf * c + si * tg;
    const float hnv = so * tanhf(cnv);
    cn[idx] = cnv;
    hn[idx] = hnv;
    hnb[idx] = f2bf(hnv);
}

// ==== M6: lh GEMM (512, dp slices 8..23) ====
__global__ __launch_bounds__(256) void m6_lh(
    const unsigned short* __restrict__ hnb, const unsigned short* __restrict__ lhb,
    float* __restrict__ dp_hi)
{
    __shared__ __align__(16) short As[2][64][72];
    __shared__ __align__(16) short Bs[2][64][72];
    const int bid = blockIdx.x;                       // 512 = 4*8*16
    GSrc s1 = {hnb, NN, lhb, NN, 16, NN};
    GSrc s2 = {nullptr, 0, nullptr, 0, 0, 0};
    gemm_body(bid & 3, (bid >> 2) & 7, bid >> 5, 4, s1, s2,
              dp_hi, MM, MM, 1, nullptr, As, Bs);
}

// ==== M7: build deep -> bf16 ====
__global__ __launch_bounds__(256) void m7_deep(
    const float* __restrict__ emb, const float* __restrict__ dp,
    const float* __restrict__ Lh_b, const float* __restrict__ Lz_b,
    unsigned short* __restrict__ deepb)
{
    const int idx = blockIdx.x * 256 + threadIdx.x;   // < B*512
    const int j = idx & 511;
    float v = emb[idx] + Lh_b[j] + Lz_b[j];
#pragma unroll
    for (int s = 0; s < 24; ++s) v += dp[(size_t)s * (BB * 512) + idx];
    deepb[idx] = f2bf(v);
}

// ==== M8: p_yt GEMM (628) ====
__global__ __launch_bounds__(256) void m8_pyt(
    const unsigned short* __restrict__ deepb, const unsigned short* __restrict__ lob,
    const float* __restrict__ Lo_b, float* __restrict__ out)
{
    __shared__ __align__(16) short As[2][64][72];
    __shared__ __align__(16) short Bs[2][64][72];
    const int bid = blockIdx.x;                       // 628 = 4*157
    GSrc s1 = {deepb, MM, lob, MM, 8, MM};
    GSrc s2 = {nullptr, 0, nullptr, 0, 0, 0};
    gemm_body(bid & 3, bid >> 2, 0, 4, s1, s2,
              out, KK, KK, 8, Lo_b, As, Bs);
}

extern "C" void kernel_launch(void* const* d_in, const int* in_sizes, int n_in,
                              void* d_out, int out_size, void* d_ws, size_t ws_size,
                              hipStream_t stream)
{
    const float* a_i     = (const float*)d_in[0];
    const float* inp     = (const float*)d_in[1];
    const float* hn_prev = (const float*)d_in[2];
    const float* cn_prev = (const float*)d_in[3];
    const float* f_att_w = (const float*)d_in[4];
    const float* f_att_b = (const float*)d_in[5];
    const float* gate_w  = (const float*)d_in[6];
    const float* gate_b  = (const float*)d_in[7];
    const float* E_w     = (const float*)d_in[8];
    const float* E_b     = (const float*)d_in[9];
    const float* W_ih    = (const float*)d_in[10];
    const float* W_hh    = (const float*)d_in[11];
    const float* b_ih    = (const float*)d_in[12];
    const float* b_hh    = (const float*)d_in[13];
    const float* Lh_w    = (const float*)d_in[14];
    const float* Lh_b    = (const float*)d_in[15];
    const float* Lz_w    = (const float*)d_in[16];
    const float* Lz_b    = (const float*)d_in[17];
    const float* Lo_w    = (const float*)d_in[18];
    const float* Lo_b    = (const float*)d_in[19];

    float* out = (float*)d_out;
    float* ws  = (float*)d_ws;

    float* PE     = ws + OFF_PE;
    float* BETA   = ws + OFF_BETA;
    float* EMB    = ws + OFF_EMB;
    float* EMBP   = ws + OFF_EMBP;
    float* GATESP = ws + OFF_GATESP;
    float* DP     = ws + OFF_DP;
    unsigned short* EWB   = (unsigned short*)(ws + OFF_EWB);
    unsigned short* WIHB  = (unsigned short*)(ws + OFF_WIHB);
    unsigned short* WHHB  = (unsigned short*)(ws + OFF_WHHB);
    unsigned short* LHB   = (unsigned short*)(ws + OFF_LHB);
    unsigned short* LZB   = (unsigned short*)(ws + OFF_LZB);
    unsigned short* LOB   = (unsigned short*)(ws + OFF_LOB);
    unsigned short* INPB  = (unsigned short*)(ws + OFF_INPB);
    unsigned short* HB    = (unsigned short*)(ws + OFF_HB);
    unsigned short* ZB    = (unsigned short*)(ws + OFF_ZB);
    unsigned short* EMBB  = (unsigned short*)(ws + OFF_EMBB);
    unsigned short* DEEPB = (unsigned short*)(ws + OFF_DEEPB);
    unsigned short* HNB   = (unsigned short*)(ws + OFF_HNB);

    // M1: att_e || cvt{E_w, inp, h}            (4096 + 486)
    m1_atte_cvt1<<<4582, 256, 0, stream>>>(a_i, f_att_w, PE,
                                           E_w, inp, hn_prev, EWB, INPB, HB);

    // M2: softmax || emb GEMM || cvt{W_ih, W_hh}  (256 + 512 + 768)
    m2_softmax_emb_cvt2<<<1536, 256, 0, stream>>>(
        PE, hn_prev, f_att_w, f_att_b, gate_w, gate_b,
        out + OUT_AL, BETA, INPB, EWB, EMBP, W_ih, W_hh, WIHB, WHHB);

    // M3: att_z || emb reduce || cvt{Lo, Lh, Lz}  (4096 + 512 + 361)
    m3_attz_embred_cvt3<<<4969, 256, 0, stream>>>(
        a_i, out + OUT_AL, BETA, ZB, EMBP, E_b, EMB, EMBB,
        Lo_w, Lh_w, Lz_w, LOB, LHB, LZB);

    // M4: gates_h || gates_e || gates_z || lz  (1024+512+512+256)
    m4_gates_lz<<<2304, 256, 0, stream>>>(HB, EMBB, ZB, WIHB, WHHB,
                                          GATESP, LZB, DP);

    // M5: LSTM cell
    m5_lstm<<<1024, 256, 0, stream>>>(GATESP, b_ih, b_hh, cn_prev,
                                      out + OUT_HN, out + OUT_CN, HNB);

    // M6: hn@Lh_w^T (dp slices 8..23)
    m6_lh<<<512, 256, 0, stream>>>(HNB, LHB, DP + (size_t)8 * BB * 512);

    // M7: deep = emb + sum(dp) + biases -> bf16
    m7_deep<<<512, 256, 0, stream>>>(EMB, DP, Lh_b, Lz_b, DEEPB);

    // M8: p_yt = deep @ Lo_w^T + Lo_b
    m8_pyt<<<628, 256, 0, stream>>>(DEEPB, LOB, Lo_b, out + OUT_PY);
}